// Round 3
// baseline (11824.384 us; speedup 1.0000x reference)
//
#include <hip/hip_runtime.h>

typedef float f32;
typedef unsigned int u32;
typedef unsigned short u16;
typedef short s16x8 __attribute__((ext_vector_type(8)));
typedef float f32x4 __attribute__((ext_vector_type(4)));
typedef u32 u32x4 __attribute__((ext_vector_type(4)));

#define S1F (-1.4426950408889634f)   /* -log2(e): r,z pre-scale */
#define S2F ( 2.8853900817779268f)   /* 2*log2(e): n pre-scale  */

__device__ __forceinline__ u16 f2bf(float x){
  u32 u = __float_as_uint(x);
  u32 r = u + 0x7FFFu + ((u >> 16) & 1u);   // round-to-nearest-even
  return (u16)(r >> 16);
}

// ---------------- meta: Lmax, prefix sums, per-branch h_src ----------------
__global__ void k_meta(const int* __restrict__ lengths, int* __restrict__ meta){
  if (threadIdx.x == 0){
    int Lmax = 0;
    for (int b=0;b<16;b++) Lmax = max(Lmax, lengths[b]);
    meta[0] = Lmax;
    int acc = 0;
    for (int b=0;b<16;b++){ meta[1+b] = acc; acc += lengths[b]; }
    meta[17] = acc;
    const int H2s[4] = {169,126,126,62};
    for (int br=0;br<4;br++)
      for (int b=0;b<16;b++){
        double ratio = (double)lengths[b] / (double)Lmax;
        meta[32 + br*16 + b] = (int)((double)H2s[br] * ratio);  // matches np trunc
      }
  }
}

// ---------------- whh -> fragment-ordered bf16 (PRE-SCALED): [set][wave8][tau6][kc8][lane64][j8] ----------------
__global__ void k_wfrag(const f32* __restrict__ w0f, const f32* __restrict__ w0b,
                        const f32* __restrict__ w1f, const f32* __restrict__ w1b,
                        u16* __restrict__ wfrag){
  int idx = blockIdx.x*256 + threadIdx.x;            // < 4*196608
  int set = idx / 196608;
  int e   = idx % 196608;
  int w   = e / 24576;  int r  = e % 24576;
  int tau = r / 4096;   int r2 = r % 4096;
  int kc  = r2 >> 9;    int r3 = r2 & 511;
  int lane= r3 >> 3;    int j  = r3 & 7;
  int g = (tau>>1)*256 + w*32 + (tau&1)*16 + (lane & 15);
  int k = kc*32 + (lane>>4)*8 + j;
  const f32* src = (set==0)? w0f : (set==1)? w0b : (set==2)? w1f : w1b;
  float scale = (tau >= 4) ? S2F : S1F;   // tau 0-3: r,z ; tau 4-5: n
  wfrag[idx] = f2bf(src[g*256 + k] * scale);
}

// ---------------- conv1 (+BN8+ReLU+maxpool2), all 8 out-channels per thread ----------------
__global__ void k_conv1(const f32* __restrict__ x, const f32* __restrict__ w, const f32* __restrict__ cb,
                        const f32* __restrict__ bg, const f32* __restrict__ bbp,
                        const f32* __restrict__ bm, const f32* __restrict__ bv,
                        f32* __restrict__ out, int K, int s, int Hp, int Wp){
  __shared__ f32 wl[8192];
  int b = blockIdx.y;
  int KK = K*K;
  for (int i=threadIdx.x; i<8*KK; i+=256) wl[i] = w[i];
  __syncthreads();
  int idx = blockIdx.x*256 + threadIdx.x;
  int npix = Hp*Wp;
  if (idx >= npix) return;
  int ph = idx / Wp, pw = idx % Wp;
  float mx[8];
  #pragma unroll
  for (int c=0;c<8;c++) mx[c] = -1e30f;
  for (int dy=0; dy<2; ++dy)
  for (int dx=0; dx<2; ++dx){
    const f32* xb = x + ((size_t)b*1024 + (size_t)(ph*2+dy)*s)*128 + (size_t)(pw*2+dx)*s;
    float acc[8];
    #pragma unroll
    for (int c=0;c<8;c++) acc[c] = 0.f;
    for (int kh=0; kh<K; ++kh){
      const f32* xr = xb + kh*128;
      for (int kw=0; kw<K; ++kw){
        float xv = xr[kw];
        #pragma unroll
        for (int c=0;c<8;c++) acc[c] = fmaf(xv, wl[c*KK + kh*K + kw], acc[c]);
      }
    }
    #pragma unroll
    for (int c=0;c<8;c++) mx[c] = fmaxf(mx[c], acc[c]);   // BN scale>0 & ReLU commute with max
  }
  #pragma unroll
  for (int c=0;c<8;c++){
    float scale = bg[c] * rsqrtf(bv[c] + 1e-5f);
    float val = (mx[c] + cb[c] - bm[c]) * scale + bbp[c];
    out[(((size_t)b*8 + c)*Hp + ph)*Wp + pw] = fmaxf(val, 0.f);
  }
}

// ---------------- conv2 (+BN3+ReLU) ----------------
__global__ void k_conv2(const f32* __restrict__ in, const f32* __restrict__ w, const f32* __restrict__ cb,
                        const f32* __restrict__ bg, const f32* __restrict__ bbp,
                        const f32* __restrict__ bm, const f32* __restrict__ bv,
                        f32* __restrict__ out, int K, int s, int Hin, int Win, int Ho, int Wo){
  __shared__ f32 wl[600];
  int b = blockIdx.y;
  int KK = K*K, sz = 24*KK;
  for (int i=threadIdx.x; i<sz; i+=256) wl[i] = w[i];
  __syncthreads();
  int idx = blockIdx.x*256 + threadIdx.x;
  int npix = Ho*Wo;
  if (idx >= npix) return;
  int oh = idx / Wo, ow = idx % Wo;
  float acc[3] = {0.f,0.f,0.f};
  for (int ci=0; ci<8; ++ci){
    const f32* xp = in + (((size_t)b*8 + ci)*Hin + (size_t)oh*s)*Win + (size_t)ow*s;
    for (int kh=0; kh<K; ++kh)
      for (int kw=0; kw<K; ++kw){
        float xv = xp[kh*Win + kw];
        #pragma unroll
        for (int co=0; co<3; ++co) acc[co] = fmaf(xv, wl[(co*8+ci)*KK + kh*K + kw], acc[co]);
      }
  }
  #pragma unroll
  for (int co=0; co<3; ++co){
    float scale = bg[co] * rsqrtf(bv[co] + 1e-5f);
    float val = (acc[co] + cb[co] - bm[co]) * scale + bbp[co];
    out[(((size_t)b*3 + co)*Ho + oh)*Wo + ow] = fmaxf(val, 0.f);
  }
}

// ---------------- per-batch bilinear resize -> flattened feats ----------------
__global__ void k_resize(const f32* __restrict__ src, const int* __restrict__ meta,
                         f32* __restrict__ feats, int H2, int W2, int Ho, int Wo, int off, int br){
  int idx = blockIdx.x*256 + threadIdx.x;
  int per_b = 3*Ho*Wo;
  if (idx >= 16*per_b) return;
  int b = idx / per_b;  int r = idx % per_b;
  int c = r / (Ho*Wo);  int r2 = r % (Ho*Wo);
  int ho = r2 / Wo, wo = r2 % Wo;
  int hs = meta[32 + br*16 + b];
  float cy = ((float)ho + 0.5f) * ((float)hs / (float)Ho) - 0.5f;
  cy = fmaxf(cy, 0.f);
  int him = hs - 1;
  int i0 = min((int)floorf(cy), him);
  int i1 = min(i0 + 1, him);
  float w1 = fminf(fmaxf(cy - (float)i0, 0.f), 1.f);
  float rw = (float)((double)W2 / (double)Wo);
  float cw = ((float)wo + 0.5f) * rw - 0.5f;
  cw = fminf(fmaxf(cw, 0.f), (float)(W2 - 1));
  int j0 = (int)floorf(cw);
  int j1 = min(j0 + 1, W2 - 1);
  float ww = cw - (float)j0;
  const f32* sp = src + (size_t)(b*3 + c) * H2 * W2;
  float v00 = sp[i0*W2 + j0], v01 = sp[i0*W2 + j1];
  float v10 = sp[i1*W2 + j0], v11 = sp[i1*W2 + j1];
  float col0 = v00*(1.f - w1) + v10*w1;
  float col1 = v01*(1.f - w1) + v11*w1;
  feats[(size_t)b*5040 + off + (c*Ho + ho)*Wo + wo] = col0*(1.f - ww) + col1*ww;
}

// ---------------- fc1: rfeat[b][o] = feats[b] . fc1_w[o] + b ----------------
__global__ void k_fc1(const f32* __restrict__ feats, const f32* __restrict__ w,
                      const f32* __restrict__ bias, f32* __restrict__ rfeat){
  int b = blockIdx.x;
  int o0 = blockIdx.y * 64;
  int sub = threadIdx.x & 31, og = threadIdx.x >> 5;
  const f32* fp = feats + (size_t)b*5040;
  for (int oi = og; oi < 64; oi += 8){
    int o = o0 + oi;
    const f32* wp = w + (size_t)o*5040;
    float acc = 0.f;
    for (int k = sub; k < 5040; k += 32) acc = fmaf(fp[k], wp[k], acc);
    #pragma unroll
    for (int m=16; m; m>>=1) acc += __shfl_xor(acc, m, 32);
    if (sub == 0) rfeat[(size_t)b*512 + o] = acc + bias[o];
  }
}

// ---------------- ydc[d][b][g] = bih[g] + rfeat[b] . wih[g, 128:640]  (layer0 time-invariant part) ----------------
__global__ void k_ydc(const f32* __restrict__ rfeat, const f32* __restrict__ wihf, const f32* __restrict__ wihb,
                      const f32* __restrict__ bihf, const f32* __restrict__ bihb, f32* __restrict__ ydc){
  int idx = blockIdx.x*256 + threadIdx.x;   // < 24576
  int d = idx / 12288;  int r = idx % 12288;
  int b = r / 768;      int g = r % 768;
  const f32* wih = d ? wihb : wihf;
  const f32* bih = d ? bihb : bihf;
  const f32* rp = rfeat + (size_t)b*512;
  const f32* wp = wih + (size_t)g*640 + 128;
  float acc = bih[g];
  for (int k=0;k<512;k++) acc = fmaf(rp[k], wp[k], acc);
  ydc[idx] = acc;
}

// ---------------- xW GEMM (bf16 MFMA): xw[dir][t][b][g] ----------------
// rows r = t*16+b (16384), cols g (768). A row gathered (bwd uses rev_idx).
// Folds bhh into r,z cols AND pre-scales gate inputs (r,z: *S1F, n: *S2F).
template<int LAYER>
__global__ __launch_bounds__(256)
void k_xw(const f32* __restrict__ A0, const f32* __restrict__ wihf, const f32* __restrict__ wihb,
          const f32* __restrict__ biasf, const f32* __restrict__ biasb,
          const f32* __restrict__ ydc, const f32* __restrict__ bhf, const f32* __restrict__ bhb,
          const int* __restrict__ lengths, f32* __restrict__ xwbuf){
  constexpr int KT   = (LAYER==0) ? 128 : 512;
  constexpr int WSTR = (LAYER==0) ? 640 : 512;
  int dir = blockIdx.z;
  const f32* wih = dir ? wihb : wihf;
  f32* out = xwbuf + (size_t)dir * 16384 * 768;
  int brow = blockIdx.x * 64, bcol = blockIdx.y * 64;
  __shared__ u32 As[1024], Bs[1024];   // 64 rows x 32 bf16 each
  int tid = threadIdx.x, lane = tid & 63, wid = tid >> 6;
  int rl = tid >> 2, kg = tid & 3;
  int grow = brow + rl;
  int tt = grow >> 4, bb = grow & 15;
  int srct = tt;
  if (dir){ int L = lengths[bb]; srct = (tt < L) ? (L - 1 - tt) : tt; }
  const f32* arow = A0 + ((size_t)bb*1024 + srct) * KT;
  const f32* brp  = wih + (size_t)(bcol + rl) * WSTR;
  int swst = kg ^ ((rl >> 1) & 3);
  u32* adst = &As[rl*16 + swst*4];
  u32* bdst = &Bs[rl*16 + swst*4];
  int r16 = wid*16 + (lane & 15);
  int grp = lane >> 4;
  int aoff = r16*16 + ((grp ^ ((r16 >> 1) & 3)) * 4);
  f32x4 acc[4];
  #pragma unroll
  for (int nt=0; nt<4; ++nt) acc[nt] = (f32x4){0.f,0.f,0.f,0.f};

  for (int kc=0; kc<KT/32; ++kc){
    int k0 = kc*32 + kg*8;
    {
      const f32* ap = arow + k0;
      u32 p0 = (u32)f2bf(ap[0]) | ((u32)f2bf(ap[1])<<16);
      u32 p1 = (u32)f2bf(ap[2]) | ((u32)f2bf(ap[3])<<16);
      u32 p2 = (u32)f2bf(ap[4]) | ((u32)f2bf(ap[5])<<16);
      u32 p3 = (u32)f2bf(ap[6]) | ((u32)f2bf(ap[7])<<16);
      u32x4 v = {p0,p1,p2,p3};
      *(u32x4*)adst = v;
      const f32* bp = brp + k0;
      u32 q0 = (u32)f2bf(bp[0]) | ((u32)f2bf(bp[1])<<16);
      u32 q1 = (u32)f2bf(bp[2]) | ((u32)f2bf(bp[3])<<16);
      u32 q2 = (u32)f2bf(bp[4]) | ((u32)f2bf(bp[5])<<16);
      u32 q3 = (u32)f2bf(bp[6]) | ((u32)f2bf(bp[7])<<16);
      u32x4 u = {q0,q1,q2,q3};
      *(u32x4*)bdst = u;
    }
    __syncthreads();
    s16x8 a = *(const s16x8*)&As[aoff];
    #pragma unroll
    for (int nt=0; nt<4; ++nt){
      int gl = nt*16 + (lane & 15);
      s16x8 bfr = *(const s16x8*)&Bs[gl*16 + ((grp ^ ((gl >> 1) & 3)) * 4)];
      acc[nt] = __builtin_amdgcn_mfma_f32_16x16x32_bf16(a, bfr, acc[nt], 0, 0, 0);
    }
    __syncthreads();
  }
  const f32* bh = dir ? bhb : bhf;
  #pragma unroll
  for (int nt=0; nt<4; ++nt){
    int col = bcol + nt*16 + (lane & 15);
    float bhadd = (col < 512) ? bh[col] : 0.f;
    float scale = (col < 512) ? S1F : S2F;
    #pragma unroll
    for (int q=0; q<4; ++q){
      int row = brow + wid*16 + (lane >> 4)*4 + q;
      float bias;
      if (LAYER == 0) bias = ydc[((size_t)dir*16 + (row & 15))*768 + col];
      else            bias = (dir ? biasb : biasf)[col];
      out[(size_t)row*768 + col] = (acc[nt][q] + bias + bhadd) * scale;
    }
  }
}

// ---------------- GRU recurrence: one block per direction ----------------
// 8 waves; wave w owns j in [32w,32w+32). ALL 6 weight tiles in registers.
// xW prefetched one full step ahead (ping-pong X0/X1). h double-buffered in
// LDS (bf16, XOR-swizzled), ONE raw barrier/step (no vmcnt drain).
__device__ __forceinline__ void loadx(const f32* (&xp)[4], float (&X)[6][4]){
  #pragma unroll
  for (int q=0;q<4;q++){
    const f32* p = xp[q];
    X[0][q]=p[0];   X[1][q]=p[16];     // r  (pre-scaled by S1F)
    X[2][q]=p[256]; X[3][q]=p[272];    // z  (pre-scaled by S1F)
    X[4][q]=p[512]; X[5][q]=p[528];    // n  (pre-scaled by S2F)
    xp[q] += 12288;
  }
}

#define GRU_STEP(t_, u_, X_) do { \
  f32x4 a_r0={0.f,0.f,0.f,0.f}, a_r1={0.f,0.f,0.f,0.f}; \
  f32x4 a_z0={0.f,0.f,0.f,0.f}, a_z1={0.f,0.f,0.f,0.f}; \
  f32x4 a_n0={bhn0,bhn0,bhn0,bhn0}, a_n1={bhn1,bhn1,bhn1,bhn1}; \
  _Pragma("unroll") \
  for (int kc=0; kc<8; ++kc){ \
    int phys = ((kc<<2) + lq) ^ l15; \
    s16x8 a = *(const s16x8*)&h_lds[(u_)*4096 + l15*256 + phys*8]; \
    a_r0 = __builtin_amdgcn_mfma_f32_16x16x32_bf16(a, wreg[0][kc], a_r0, 0,0,0); \
    a_r1 = __builtin_amdgcn_mfma_f32_16x16x32_bf16(a, wreg[1][kc], a_r1, 0,0,0); \
    a_z0 = __builtin_amdgcn_mfma_f32_16x16x32_bf16(a, wreg[2][kc], a_z0, 0,0,0); \
    a_z1 = __builtin_amdgcn_mfma_f32_16x16x32_bf16(a, wreg[3][kc], a_z1, 0,0,0); \
    a_n0 = __builtin_amdgcn_mfma_f32_16x16x32_bf16(a, wreg[4][kc], a_n0, 0,0,0); \
    a_n1 = __builtin_amdgcn_mfma_f32_16x16x32_bf16(a, wreg[5][kc], a_n1, 0,0,0); \
  } \
  _Pragma("unroll") \
  for (int q=0;q<4;q++){ \
    float r0 = __builtin_amdgcn_rcpf(1.0f + __builtin_amdgcn_exp2f(X_[0][q] + a_r0[q])); \
    float z0 = __builtin_amdgcn_rcpf(1.0f + __builtin_amdgcn_exp2f(X_[2][q] + a_z0[q])); \
    float n0 = fmaf(-2.0f, __builtin_amdgcn_rcpf(__builtin_amdgcn_exp2f(fmaf(r0, a_n0[q], X_[4][q])) + 1.0f), 1.0f); \
    float h0v = fmaf(z0, hp0[q] - n0, n0); \
    hp0[q] = h0v; \
    float r1 = __builtin_amdgcn_rcpf(1.0f + __builtin_amdgcn_exp2f(X_[1][q] + a_r1[q])); \
    float z1 = __builtin_amdgcn_rcpf(1.0f + __builtin_amdgcn_exp2f(X_[3][q] + a_z1[q])); \
    float n1 = fmaf(-2.0f, __builtin_amdgcn_rcpf(__builtin_amdgcn_exp2f(fmaf(r1, a_n1[q], X_[5][q])) + 1.0f), 1.0f); \
    float h1v = fmaf(z1, hp1[q] - n1, n1); \
    hp1[q] = h1v; \
    int b = bq + q; \
    u32 ub0 = __float_as_uint(h0v), ub1 = __float_as_uint(h1v); \
    h_lds[((u_)^1)*4096 + b*256 + ((g0 ^ b)<<3) + e7]     = (u16)((ub0 + 0x8000u)>>16); \
    h_lds[((u_)^1)*4096 + b*256 + (((g0+2) ^ b)<<3) + e7] = (u16)((ub1 + 0x8000u)>>16); \
    if (dir == 0){ hpt[q][0]=h0v; hpt[q][16]=h1v; hpt[q]+=512; } \
    else { int tpos = ((t_) < Lb[q]) ? (Lb[q]-1-(t_)) : (t_); \
           hpt[q][(size_t)tpos*512]=h0v; hpt[q][(size_t)tpos*512+16]=h1v; } \
  } \
  asm volatile("s_waitcnt lgkmcnt(0)\n\ts_barrier" ::: "memory"); \
} while(0)

template<int LAYER>
__global__ __launch_bounds__(512, 1)
void k_recur(const f32* __restrict__ xw, const u16* __restrict__ wfrag,
             const f32* __restrict__ bhhf, const f32* __restrict__ bhhb,
             const int* __restrict__ lengths, f32* __restrict__ hout){
  __shared__ u16 h_lds[8192];     // 2 buffers x (16 rows x 256 bf16), XOR-swizzled 16B groups
  const int dir = blockIdx.x;
  const int tid = threadIdx.x, lane = tid & 63, wid = tid >> 6;
  const f32* xwd = xw + (size_t)dir * 12582912;
  const f32* bhh = dir ? bhhb : bhhf;
  const u16* wf = wfrag + (size_t)(LAYER*2 + dir) * 196608;

  // all 6 tiles (r0,r1,z0,z1,n0,n1) resident in registers
  s16x8 wreg[6][8];
  #pragma unroll
  for (int tau=0; tau<6; ++tau)
    #pragma unroll
    for (int kc=0; kc<8; ++kc)
      wreg[tau][kc] = *(const s16x8*)(wf + ((size_t)((wid*6+tau)*8 + kc)*64 + lane)*8);
  for (int i=tid; i<4096; i+=512) ((u32*)h_lds)[i] = 0;

  const int l15 = lane & 15, lq = lane >> 4;
  const int jlo = (wid << 5) + l15;     // j for tp=0 (tp=1 is +16)
  const int bq  = lq * 4;
  const float bhn0 = bhh[512 + jlo] * S2F;
  const float bhn1 = bhh[512 + jlo + 16] * S2F;
  int Lb[4];
  #pragma unroll
  for (int q=0;q<4;q++) Lb[q] = lengths[bq + q];
  float hp0[4], hp1[4];
  #pragma unroll
  for (int q=0;q<4;q++){ hp0[q]=0.f; hp1[q]=0.f; }

  const f32* xp[4];
  #pragma unroll
  for (int q=0;q<4;q++) xp[q] = xwd + (size_t)(bq+q)*768 + jlo;
  f32* hpt[4];
  #pragma unroll
  for (int q=0;q<4;q++) hpt[q] = hout + (size_t)(bq+q)*1024*512 + dir*256 + jlo;

  const int g0 = (wid << 2) + (l15 >> 3);   // logical group of j=jlo within row
  const int e7 = l15 & 7;

  float X0[6][4], X1[6][4];
  loadx(xp, X0);              // t=0 (in flight across the sync)
  __syncthreads();

  for (int t2=0; t2<1024; t2+=2){
    loadx(xp, X1);            // prefetch t2+1 (full step of latency cover)
    GRU_STEP(t2,   0, X0);
    loadx(xp, X0);            // prefetch t2+2 (overreads 48KB past end on last iter: ws-safe)
    GRU_STEP(t2+1, 1, X1);
  }
}

// ---------------- final FC + length gather ----------------
__global__ void k_final(const f32* __restrict__ h1, const f32* __restrict__ fcw, const f32* __restrict__ fcb,
                        const int* __restrict__ lengths, const int* __restrict__ meta, f32* __restrict__ out){
  int t = blockIdx.x, b = blockIdx.y;
  if (t >= lengths[b]) return;
  __shared__ f32 part[4][64];
  int lane = threadIdx.x & 63, q = threadIdx.x >> 6;
  float acc = 0.f;
  if (lane < 61){
    const f32* wp = fcw + (size_t)lane*512 + q*128;
    const f32* hp = h1 + ((size_t)b*1024 + t)*512 + q*128;
    for (int k=0;k<128;k++) acc = fmaf(hp[k], wp[k], acc);
  }
  part[q][lane] = acc;
  __syncthreads();
  if (q == 0 && lane < 61){
    int row = meta[1 + b] + t;
    out[(size_t)row*61 + lane] = part[0][lane] + part[1][lane] + part[2][lane] + part[3][lane] + fcb[lane];
  }
}

// ---------------- host ----------------
extern "C" void kernel_launch(void* const* d_in, const int* in_sizes, int n_in,
                              void* d_out, int out_size, void* d_ws, size_t ws_size,
                              hipStream_t stream){
  const f32* batch = (const f32*)d_in[0];
  const f32* c1w[4] = {(const f32*)d_in[1],(const f32*)d_in[3],(const f32*)d_in[5],(const f32*)d_in[7]};
  const f32* c1b[4] = {(const f32*)d_in[2],(const f32*)d_in[4],(const f32*)d_in[6],(const f32*)d_in[8]};
  const f32* c2w[4] = {(const f32*)d_in[9],(const f32*)d_in[11],(const f32*)d_in[13],(const f32*)d_in[15]};
  const f32* c2b[4] = {(const f32*)d_in[10],(const f32*)d_in[12],(const f32*)d_in[14],(const f32*)d_in[16]};
  const f32 *bn8g=(const f32*)d_in[17], *bn8b=(const f32*)d_in[18], *bn8m=(const f32*)d_in[19], *bn8v=(const f32*)d_in[20];
  const f32 *bn3g=(const f32*)d_in[21], *bn3b=(const f32*)d_in[22], *bn3m=(const f32*)d_in[23], *bn3v=(const f32*)d_in[24];
  const f32 *fc1w=(const f32*)d_in[25], *fc1b=(const f32*)d_in[26];
  const f32 *g0f_wih=(const f32*)d_in[27], *g0f_whh=(const f32*)d_in[28], *g0f_bih=(const f32*)d_in[29], *g0f_bhh=(const f32*)d_in[30];
  const f32 *g0b_wih=(const f32*)d_in[31], *g0b_whh=(const f32*)d_in[32], *g0b_bih=(const f32*)d_in[33], *g0b_bhh=(const f32*)d_in[34];
  const f32 *g1f_wih=(const f32*)d_in[35], *g1f_whh=(const f32*)d_in[36], *g1f_bih=(const f32*)d_in[37], *g1f_bhh=(const f32*)d_in[38];
  const f32 *g1b_wih=(const f32*)d_in[39], *g1b_whh=(const f32*)d_in[40], *g1b_bih=(const f32*)d_in[41], *g1b_bhh=(const f32*)d_in[42];
  const f32 *fcw=(const f32*)d_in[43], *fcb=(const f32*)d_in[44];
  const int* lengths = (const int*)d_in[45];
  f32* out = (f32*)d_out;

  char* base = (char*)d_ws;
  size_t off = 0;
  auto alloc = [&](size_t bytes)->void*{
    void* p = base + off;
    off += bytes;
    off = (off + 255) & ~(size_t)255;
    return p;
  };

  static const int Hp[4]={510,254,126,62}, Wpp[4]={62,30,14,6};
  static const int K1[4]={4,8,16,32}, S1[4]={1,2,4,8};
  static const int K2[4]={5,3,1,1},  S2[4]={3,2,1,1};
  static const int Ho2[4]={169,126,126,62}, Wo2[4]={20,14,14,6};
  static const int Hr[4]={90,67,67,33}, Wr[4]={9,6,6,2};
  static const int Foff[4]={0,2430,3636,4842};

  f32* r1[4]; for (int i=0;i<4;i++) r1[i] = (f32*)alloc((size_t)16*8*Hp[i]*Wpp[i]*4);
  f32* r2[4]; for (int i=0;i<4;i++) r2[i] = (f32*)alloc((size_t)16*3*Ho2[i]*Wo2[i]*4);
  f32* feats = (f32*)alloc((size_t)16*5040*4);
  f32* rfeat = (f32*)alloc((size_t)16*512*4);
  f32* ydc   = (f32*)alloc((size_t)2*16*768*4);
  int* meta  = (int*)alloc(128*4);
  u16* wfrag = (u16*)alloc((size_t)4*196608*2);
  f32* xwb   = (f32*)alloc((size_t)2*1024*16*768*4);
  f32* h0    = (f32*)alloc((size_t)16*1024*512*4);
  f32* h1p   = (f32*)alloc((size_t)16*1024*512*4);

  k_meta<<<1,64,0,stream>>>(lengths, meta);
  k_wfrag<<<3072,256,0,stream>>>(g0f_whh, g0b_whh, g1f_whh, g1b_whh, wfrag);
  for (int i=0;i<4;i++){
    int np = Hp[i]*Wpp[i];
    k_conv1<<<dim3((np+255)/256,16),256,0,stream>>>(batch, c1w[i], c1b[i], bn8g,bn8b,bn8m,bn8v,
                                                    r1[i], K1[i], S1[i], Hp[i], Wpp[i]);
  }
  for (int i=0;i<4;i++){
    int np = Ho2[i]*Wo2[i];
    k_conv2<<<dim3((np+255)/256,16),256,0,stream>>>(r1[i], c2w[i], c2b[i], bn3g,bn3b,bn3m,bn3v,
                                                    r2[i], K2[i], S2[i], Hp[i], Wpp[i], Ho2[i], Wo2[i]);
  }
  for (int i=0;i<4;i++){
    int tot = 16*3*Hr[i]*Wr[i];
    k_resize<<<(tot+255)/256,256,0,stream>>>(r2[i], meta, feats, Ho2[i], Wo2[i], Hr[i], Wr[i], Foff[i], i);
  }
  k_fc1<<<dim3(16,8),256,0,stream>>>(feats, fc1w, fc1b, rfeat);
  k_ydc<<<96,256,0,stream>>>(rfeat, g0f_wih, g0b_wih, g0f_bih, g0b_bih, ydc);
  k_xw<0><<<dim3(256,12,2),256,0,stream>>>(batch, g0f_wih, g0b_wih, nullptr, nullptr, ydc, g0f_bhh, g0b_bhh, lengths, xwb);
  k_recur<0><<<2,512,0,stream>>>(xwb, wfrag, g0f_bhh, g0b_bhh, lengths, h0);
  k_xw<1><<<dim3(256,12,2),256,0,stream>>>(h0, g1f_wih, g1b_wih, g1f_bih, g1b_bih, nullptr, g1f_bhh, g1b_bhh, lengths, xwb);
  k_recur<1><<<2,512,0,stream>>>(xwb, wfrag, g1f_bhh, g1b_bhh, lengths, h1p);
  k_final<<<dim3(1024,16),256,0,stream>>>(h1p, fcw, fcb, lengths, meta, out);
}

// Round 4
// 4264.138 us; speedup vs baseline: 2.7730x; 2.7730x over previous
//
#include <hip/hip_runtime.h>

typedef float f32;
typedef unsigned int u32;
typedef unsigned short u16;
typedef short s16x8 __attribute__((ext_vector_type(8)));
typedef float f32x4 __attribute__((ext_vector_type(4)));
typedef u32 u32x4 __attribute__((ext_vector_type(4)));

#define S1F (-1.4426950408889634f)   /* -log2(e): r,z pre-scale */
#define S2F ( 2.8853900817779268f)   /* 2*log2(e): n pre-scale  */

__device__ __forceinline__ u16 f2bf(float x){
  u32 u = __float_as_uint(x);
  u32 r = u + 0x7FFFu + ((u >> 16) & 1u);   // round-to-nearest-even
  return (u16)(r >> 16);
}

// ---------------- meta: Lmax, prefix sums, per-branch h_src ----------------
__global__ void k_meta(const int* __restrict__ lengths, int* __restrict__ meta){
  if (threadIdx.x == 0){
    int Lmax = 0;
    for (int b=0;b<16;b++) Lmax = max(Lmax, lengths[b]);
    meta[0] = Lmax;
    int acc = 0;
    for (int b=0;b<16;b++){ meta[1+b] = acc; acc += lengths[b]; }
    meta[17] = acc;
    const int H2s[4] = {169,126,126,62};
    for (int br=0;br<4;br++)
      for (int b=0;b<16;b++){
        double ratio = (double)lengths[b] / (double)Lmax;
        meta[32 + br*16 + b] = (int)((double)H2s[br] * ratio);  // matches np trunc
      }
  }
}

// ---------------- whh -> fragment-ordered bf16 (PRE-SCALED): [set][wave8][tau6][kc8][lane64][j8] ----------------
__global__ void k_wfrag(const f32* __restrict__ w0f, const f32* __restrict__ w0b,
                        const f32* __restrict__ w1f, const f32* __restrict__ w1b,
                        u16* __restrict__ wfrag){
  int idx = blockIdx.x*256 + threadIdx.x;            // < 4*196608
  int set = idx / 196608;
  int e   = idx % 196608;
  int w   = e / 24576;  int r  = e % 24576;
  int tau = r / 4096;   int r2 = r % 4096;
  int kc  = r2 >> 9;    int r3 = r2 & 511;
  int lane= r3 >> 3;    int j  = r3 & 7;
  int g = (tau>>1)*256 + w*32 + (tau&1)*16 + (lane & 15);
  int k = kc*32 + (lane>>4)*8 + j;
  const f32* src = (set==0)? w0f : (set==1)? w0b : (set==2)? w1f : w1b;
  float scale = (tau >= 4) ? S2F : S1F;   // tau 0-3: r,z ; tau 4-5: n
  wfrag[idx] = f2bf(src[g*256 + k] * scale);
}

// ---------------- conv1 (+BN8+ReLU+maxpool2), all 8 out-channels per thread ----------------
__global__ void k_conv1(const f32* __restrict__ x, const f32* __restrict__ w, const f32* __restrict__ cb,
                        const f32* __restrict__ bg, const f32* __restrict__ bbp,
                        const f32* __restrict__ bm, const f32* __restrict__ bv,
                        f32* __restrict__ out, int K, int s, int Hp, int Wp){
  __shared__ f32 wl[8192];
  int b = blockIdx.y;
  int KK = K*K;
  for (int i=threadIdx.x; i<8*KK; i+=256) wl[i] = w[i];
  __syncthreads();
  int idx = blockIdx.x*256 + threadIdx.x;
  int npix = Hp*Wp;
  if (idx >= npix) return;
  int ph = idx / Wp, pw = idx % Wp;
  float mx[8];
  #pragma unroll
  for (int c=0;c<8;c++) mx[c] = -1e30f;
  for (int dy=0; dy<2; ++dy)
  for (int dx=0; dx<2; ++dx){
    const f32* xb = x + ((size_t)b*1024 + (size_t)(ph*2+dy)*s)*128 + (size_t)(pw*2+dx)*s;
    float acc[8];
    #pragma unroll
    for (int c=0;c<8;c++) acc[c] = 0.f;
    for (int kh=0; kh<K; ++kh){
      const f32* xr = xb + kh*128;
      for (int kw=0; kw<K; ++kw){
        float xv = xr[kw];
        #pragma unroll
        for (int c=0;c<8;c++) acc[c] = fmaf(xv, wl[c*KK + kh*K + kw], acc[c]);
      }
    }
    #pragma unroll
    for (int c=0;c<8;c++) mx[c] = fmaxf(mx[c], acc[c]);   // BN scale>0 & ReLU commute with max
  }
  #pragma unroll
  for (int c=0;c<8;c++){
    float scale = bg[c] * rsqrtf(bv[c] + 1e-5f);
    float val = (mx[c] + cb[c] - bm[c]) * scale + bbp[c];
    out[(((size_t)b*8 + c)*Hp + ph)*Wp + pw] = fmaxf(val, 0.f);
  }
}

// ---------------- conv2 (+BN3+ReLU) ----------------
__global__ void k_conv2(const f32* __restrict__ in, const f32* __restrict__ w, const f32* __restrict__ cb,
                        const f32* __restrict__ bg, const f32* __restrict__ bbp,
                        const f32* __restrict__ bm, const f32* __restrict__ bv,
                        f32* __restrict__ out, int K, int s, int Hin, int Win, int Ho, int Wo){
  __shared__ f32 wl[600];
  int b = blockIdx.y;
  int KK = K*K, sz = 24*KK;
  for (int i=threadIdx.x; i<sz; i+=256) wl[i] = w[i];
  __syncthreads();
  int idx = blockIdx.x*256 + threadIdx.x;
  int npix = Ho*Wo;
  if (idx >= npix) return;
  int oh = idx / Wo, ow = idx % Wo;
  float acc[3] = {0.f,0.f,0.f};
  for (int ci=0; ci<8; ++ci){
    const f32* xp = in + (((size_t)b*8 + ci)*Hin + (size_t)oh*s)*Win + (size_t)ow*s;
    for (int kh=0; kh<K; ++kh)
      for (int kw=0; kw<K; ++kw){
        float xv = xp[kh*Win + kw];
        #pragma unroll
        for (int co=0; co<3; ++co) acc[co] = fmaf(xv, wl[(co*8+ci)*KK + kh*K + kw], acc[co]);
      }
  }
  #pragma unroll
  for (int co=0; co<3; ++co){
    float scale = bg[co] * rsqrtf(bv[co] + 1e-5f);
    float val = (acc[co] + cb[co] - bm[co]) * scale + bbp[co];
    out[(((size_t)b*3 + co)*Ho + oh)*Wo + ow] = fmaxf(val, 0.f);
  }
}

// ---------------- per-batch bilinear resize -> flattened feats ----------------
__global__ void k_resize(const f32* __restrict__ src, const int* __restrict__ meta,
                         f32* __restrict__ feats, int H2, int W2, int Ho, int Wo, int off, int br){
  int idx = blockIdx.x*256 + threadIdx.x;
  int per_b = 3*Ho*Wo;
  if (idx >= 16*per_b) return;
  int b = idx / per_b;  int r = idx % per_b;
  int c = r / (Ho*Wo);  int r2 = r % (Ho*Wo);
  int ho = r2 / Wo, wo = r2 % Wo;
  int hs = meta[32 + br*16 + b];
  float cy = ((float)ho + 0.5f) * ((float)hs / (float)Ho) - 0.5f;
  cy = fmaxf(cy, 0.f);
  int him = hs - 1;
  int i0 = min((int)floorf(cy), him);
  int i1 = min(i0 + 1, him);
  float w1 = fminf(fmaxf(cy - (float)i0, 0.f), 1.f);
  float rw = (float)((double)W2 / (double)Wo);
  float cw = ((float)wo + 0.5f) * rw - 0.5f;
  cw = fminf(fmaxf(cw, 0.f), (float)(W2 - 1));
  int j0 = (int)floorf(cw);
  int j1 = min(j0 + 1, W2 - 1);
  float ww = cw - (float)j0;
  const f32* sp = src + (size_t)(b*3 + c) * H2 * W2;
  float v00 = sp[i0*W2 + j0], v01 = sp[i0*W2 + j1];
  float v10 = sp[i1*W2 + j0], v11 = sp[i1*W2 + j1];
  float col0 = v00*(1.f - w1) + v10*w1;
  float col1 = v01*(1.f - w1) + v11*w1;
  feats[(size_t)b*5040 + off + (c*Ho + ho)*Wo + wo] = col0*(1.f - ww) + col1*ww;
}

// ---------------- fc1: rfeat[b][o] = feats[b] . fc1_w[o] + b ----------------
__global__ void k_fc1(const f32* __restrict__ feats, const f32* __restrict__ w,
                      const f32* __restrict__ bias, f32* __restrict__ rfeat){
  int b = blockIdx.x;
  int o0 = blockIdx.y * 64;
  int sub = threadIdx.x & 31, og = threadIdx.x >> 5;
  const f32* fp = feats + (size_t)b*5040;
  for (int oi = og; oi < 64; oi += 8){
    int o = o0 + oi;
    const f32* wp = w + (size_t)o*5040;
    float acc = 0.f;
    for (int k = sub; k < 5040; k += 32) acc = fmaf(fp[k], wp[k], acc);
    #pragma unroll
    for (int m=16; m; m>>=1) acc += __shfl_xor(acc, m, 32);
    if (sub == 0) rfeat[(size_t)b*512 + o] = acc + bias[o];
  }
}

// ---------------- ydc[d][b][g] = bih[g] + rfeat[b] . wih[g, 128:640]  (layer0 time-invariant part) ----------------
__global__ void k_ydc(const f32* __restrict__ rfeat, const f32* __restrict__ wihf, const f32* __restrict__ wihb,
                      const f32* __restrict__ bihf, const f32* __restrict__ bihb, f32* __restrict__ ydc){
  int idx = blockIdx.x*256 + threadIdx.x;   // < 24576
  int d = idx / 12288;  int r = idx % 12288;
  int b = r / 768;      int g = r % 768;
  const f32* wih = d ? wihb : wihf;
  const f32* bih = d ? bihb : bihf;
  const f32* rp = rfeat + (size_t)b*512;
  const f32* wp = wih + (size_t)g*640 + 128;
  float acc = bih[g];
  for (int k=0;k<512;k++) acc = fmaf(rp[k], wp[k], acc);
  ydc[idx] = acc;
}

// ---------------- xW GEMM (bf16 MFMA): xw[dir][t][b][g] ----------------
// rows r = t*16+b (16384), cols g (768). A row gathered (bwd uses rev_idx).
// Folds bhh into r,z cols AND pre-scales gate inputs (r,z: *S1F, n: *S2F).
template<int LAYER>
__global__ __launch_bounds__(256)
void k_xw(const f32* __restrict__ A0, const f32* __restrict__ wihf, const f32* __restrict__ wihb,
          const f32* __restrict__ biasf, const f32* __restrict__ biasb,
          const f32* __restrict__ ydc, const f32* __restrict__ bhf, const f32* __restrict__ bhb,
          const int* __restrict__ lengths, f32* __restrict__ xwbuf){
  constexpr int KT   = (LAYER==0) ? 128 : 512;
  constexpr int WSTR = (LAYER==0) ? 640 : 512;
  int dir = blockIdx.z;
  const f32* wih = dir ? wihb : wihf;
  f32* out = xwbuf + (size_t)dir * 16384 * 768;
  int brow = blockIdx.x * 64, bcol = blockIdx.y * 64;
  __shared__ u32 As[1024], Bs[1024];   // 64 rows x 32 bf16 each
  int tid = threadIdx.x, lane = tid & 63, wid = tid >> 6;
  int rl = tid >> 2, kg = tid & 3;
  int grow = brow + rl;
  int tt = grow >> 4, bb = grow & 15;
  int srct = tt;
  if (dir){ int L = lengths[bb]; srct = (tt < L) ? (L - 1 - tt) : tt; }
  const f32* arow = A0 + ((size_t)bb*1024 + srct) * KT;
  const f32* brp  = wih + (size_t)(bcol + rl) * WSTR;
  int swst = kg ^ ((rl >> 1) & 3);
  u32* adst = &As[rl*16 + swst*4];
  u32* bdst = &Bs[rl*16 + swst*4];
  int r16 = wid*16 + (lane & 15);
  int grp = lane >> 4;
  int aoff = r16*16 + ((grp ^ ((r16 >> 1) & 3)) * 4);
  f32x4 acc[4];
  #pragma unroll
  for (int nt=0; nt<4; ++nt) acc[nt] = (f32x4){0.f,0.f,0.f,0.f};

  for (int kc=0; kc<KT/32; ++kc){
    int k0 = kc*32 + kg*8;
    {
      const f32* ap = arow + k0;
      u32 p0 = (u32)f2bf(ap[0]) | ((u32)f2bf(ap[1])<<16);
      u32 p1 = (u32)f2bf(ap[2]) | ((u32)f2bf(ap[3])<<16);
      u32 p2 = (u32)f2bf(ap[4]) | ((u32)f2bf(ap[5])<<16);
      u32 p3 = (u32)f2bf(ap[6]) | ((u32)f2bf(ap[7])<<16);
      u32x4 v = {p0,p1,p2,p3};
      *(u32x4*)adst = v;
      const f32* bp = brp + k0;
      u32 q0 = (u32)f2bf(bp[0]) | ((u32)f2bf(bp[1])<<16);
      u32 q1 = (u32)f2bf(bp[2]) | ((u32)f2bf(bp[3])<<16);
      u32 q2 = (u32)f2bf(bp[4]) | ((u32)f2bf(bp[5])<<16);
      u32 q3 = (u32)f2bf(bp[6]) | ((u32)f2bf(bp[7])<<16);
      u32x4 u = {q0,q1,q2,q3};
      *(u32x4*)bdst = u;
    }
    __syncthreads();
    s16x8 a = *(const s16x8*)&As[aoff];
    #pragma unroll
    for (int nt=0; nt<4; ++nt){
      int gl = nt*16 + (lane & 15);
      s16x8 bfr = *(const s16x8*)&Bs[gl*16 + ((grp ^ ((gl >> 1) & 3)) * 4)];
      acc[nt] = __builtin_amdgcn_mfma_f32_16x16x32_bf16(a, bfr, acc[nt], 0, 0, 0);
    }
    __syncthreads();
  }
  const f32* bh = dir ? bhb : bhf;
  #pragma unroll
  for (int nt=0; nt<4; ++nt){
    int col = bcol + nt*16 + (lane & 15);
    float bhadd = (col < 512) ? bh[col] : 0.f;
    float scale = (col < 512) ? S1F : S2F;
    #pragma unroll
    for (int q=0; q<4; ++q){
      int row = brow + wid*16 + (lane >> 4)*4 + q;
      float bias;
      if (LAYER == 0) bias = ydc[((size_t)dir*16 + (row & 15))*768 + col];
      else            bias = (dir ? biasb : biasf)[col];
      out[(size_t)row*768 + col] = (acc[nt][q] + bias + bhadd) * scale;
    }
  }
}

// ---------------- GRU recurrence: 2 dirs x 8 batch-groups = 16 blocks ----------------
// Each block: 2 batches, full j (8 waves x 32 j). Streams only 6KB/step of xW
// (per-CU HBM-stream was the round-2 bottleneck: 48KB/step @14.4GB/s = 3.3us/step).
// Weights: 5 tiles in regs/AGPRs + n1 tile in LDS (round-2 proven codegen).
// X prefetch: 2 sets x 12 regs, ~2 steps of latency cover. One raw barrier/step.
__device__ __forceinline__ void loadx2(const f32* (&xp)[2], float (&X)[2][6], bool act){
  if (act){
    #pragma unroll
    for (int q=0;q<2;q++){
      const f32* p = xp[q];
      X[q][0]=p[0];   X[q][1]=p[16];     // r (pre-scaled S1F)
      X[q][2]=p[256]; X[q][3]=p[272];    // z (pre-scaled S1F)
      X[q][4]=p[512]; X[q][5]=p[528];    // n (pre-scaled S2F)
    }
  }
  #pragma unroll
  for (int q=0;q<2;q++) xp[q] += 12288;
}

#define GRU_STEP(t_, u_, X_) do { \
  f32x4 a_r0={0.f,0.f,0.f,0.f}, a_r1={0.f,0.f,0.f,0.f}; \
  f32x4 a_z0={0.f,0.f,0.f,0.f}, a_z1={0.f,0.f,0.f,0.f}; \
  f32x4 a_n0={bhn0,bhn0,bhn0,bhn0}, a_n1={bhn1,bhn1,bhn1,bhn1}; \
  _Pragma("unroll") \
  for (int kc=0; kc<8; ++kc){ \
    int phys = ((kc<<2) + lq) ^ l15; \
    s16x8 a  = *(const s16x8*)&h_lds[(u_)*4096 + l15*256 + phys*8]; \
    s16x8 b5 = *(const s16x8*)&n_lds[(wid*64 + kc*8)*64 + lane*8]; \
    a_r0 = __builtin_amdgcn_mfma_f32_16x16x32_bf16(a, wreg[0][kc], a_r0, 0,0,0); \
    a_r1 = __builtin_amdgcn_mfma_f32_16x16x32_bf16(a, wreg[1][kc], a_r1, 0,0,0); \
    a_z0 = __builtin_amdgcn_mfma_f32_16x16x32_bf16(a, wreg[2][kc], a_z0, 0,0,0); \
    a_z1 = __builtin_amdgcn_mfma_f32_16x16x32_bf16(a, wreg[3][kc], a_z1, 0,0,0); \
    a_n0 = __builtin_amdgcn_mfma_f32_16x16x32_bf16(a, wreg[4][kc], a_n0, 0,0,0); \
    a_n1 = __builtin_amdgcn_mfma_f32_16x16x32_bf16(a, b5,          a_n1, 0,0,0); \
  } \
  if (lq == 0){ \
    _Pragma("unroll") \
    for (int q=0;q<2;q++){ \
      float ar0 = (q==0)? a_r0[0] : a_r0[1];  float ar1 = (q==0)? a_r1[0] : a_r1[1]; \
      float az0 = (q==0)? a_z0[0] : a_z0[1];  float az1 = (q==0)? a_z1[0] : a_z1[1]; \
      float an0 = (q==0)? a_n0[0] : a_n0[1];  float an1 = (q==0)? a_n1[0] : a_n1[1]; \
      float r0 = __builtin_amdgcn_rcpf(1.0f + __builtin_amdgcn_exp2f(X_[q][0] + ar0)); \
      float z0 = __builtin_amdgcn_rcpf(1.0f + __builtin_amdgcn_exp2f(X_[q][2] + az0)); \
      float n0 = fmaf(-2.0f, __builtin_amdgcn_rcpf(__builtin_amdgcn_exp2f(fmaf(r0, an0, X_[q][4])) + 1.0f), 1.0f); \
      float h0v = fmaf(z0, hp[q][0] - n0, n0); \
      hp[q][0] = h0v; \
      float r1 = __builtin_amdgcn_rcpf(1.0f + __builtin_amdgcn_exp2f(X_[q][1] + ar1)); \
      float z1 = __builtin_amdgcn_rcpf(1.0f + __builtin_amdgcn_exp2f(X_[q][3] + az1)); \
      float n1 = fmaf(-2.0f, __builtin_amdgcn_rcpf(__builtin_amdgcn_exp2f(fmaf(r1, an1, X_[q][5])) + 1.0f), 1.0f); \
      float h1v = fmaf(z1, hp[q][1] - n1, n1); \
      hp[q][1] = h1v; \
      u32 ub0 = __float_as_uint(h0v), ub1 = __float_as_uint(h1v); \
      h_lds[((u_)^1)*4096 + q*256 + ((g0 ^ q)<<3) + e7]       = (u16)((ub0 + 0x8000u)>>16); \
      h_lds[((u_)^1)*4096 + q*256 + (((g0+2) ^ q)<<3) + e7]   = (u16)((ub1 + 0x8000u)>>16); \
      if (dir == 0){ \
        hpt[q][0] = h0v; hpt[q][16] = h1v; hpt[q] += 512; \
      } else { \
        int tpos = ((t_) < Lb[q]) ? (Lb[q]-1-(t_)) : (t_); \
        hpt[q][(size_t)tpos*512]      = h0v; \
        hpt[q][(size_t)tpos*512 + 16] = h1v; \
      } \
    } \
  } \
  asm volatile("s_waitcnt lgkmcnt(0)\n\ts_barrier" ::: "memory"); \
} while(0)

template<int LAYER>
__global__ __launch_bounds__(512, 2)
void k_recur(const f32* __restrict__ xw, const u16* __restrict__ wfrag,
             const f32* __restrict__ bhhf, const f32* __restrict__ bhhb,
             const int* __restrict__ lengths, f32* __restrict__ hout){
  __shared__ u16 h_lds[8192];     // 2 bufs x (16 rows x 256 bf16), XOR-swizzled 16B groups
  __shared__ u16 n_lds[32768];    // 8 waves x 4KB: n1 weight tile, fragment-ordered
  const int dir = blockIdx.y;
  const int b0  = blockIdx.x * 2;           // this block's batches: b0, b0+1
  const int tid = threadIdx.x, lane = tid & 63, wid = tid >> 6;
  const f32* xwd = xw + (size_t)dir * 12582912;
  const f32* bhh = dir ? bhhb : bhhf;
  const u16* wf = wfrag + (size_t)(LAYER*2 + dir) * 196608;

  // tiles tau=0..4 (r0,r1,z0,z1,n0) resident in regs/AGPRs; tau=5 (n1) -> LDS
  s16x8 wreg[5][8];
  #pragma unroll
  for (int tau=0; tau<5; ++tau)
    #pragma unroll
    for (int kc=0; kc<8; ++kc)
      wreg[tau][kc] = *(const s16x8*)(wf + ((size_t)((wid*6+tau)*8 + kc)*64 + lane)*8);
  #pragma unroll
  for (int kc=0; kc<8; ++kc){
    s16x8 v = *(const s16x8*)(wf + ((size_t)((wid*6+5)*8 + kc)*64 + lane)*8);
    *(s16x8*)&n_lds[((size_t)wid*64 + (size_t)kc*8)*64 + (size_t)lane*8] = v;
  }
  for (int i=tid; i<4096; i+=512) ((u32*)h_lds)[i] = 0;

  const int l15 = lane & 15, lq = lane >> 4;
  const int jlo = (wid << 5) + l15;     // j for tp=0 (tp=1 is +16)
  const float bhn0 = bhh[512 + jlo] * S2F;
  const float bhn1 = bhh[512 + jlo + 16] * S2F;
  int Lb[2] = { lengths[b0], lengths[b0+1] };
  float hp[2][2] = {{0.f,0.f},{0.f,0.f}};   // [q][tp]

  const bool ldact = (lq == 0);
  const f32* xp[2];
  #pragma unroll
  for (int q=0;q<2;q++) xp[q] = xwd + (size_t)(b0+q)*768 + jlo;
  f32* hpt[2];
  #pragma unroll
  for (int q=0;q<2;q++) hpt[q] = hout + (size_t)(b0+q)*1024*512 + dir*256 + jlo;

  const int g0 = (wid << 2) + (l15 >> 3);   // logical 8-elem group of j=jlo within row
  const int e7 = l15 & 7;

  float X0[2][6], X1[2][6];
  loadx2(xp, X0, ldact);      // t=0
  loadx2(xp, X1, ldact);      // t=1
  __syncthreads();

  for (int t2=0; t2<1024; t2+=2){
    GRU_STEP(t2,   0, X0);
    loadx2(xp, X0, ldact);    // t2+2 (last iter overreads <=96KB into next ws region: safe)
    GRU_STEP(t2+1, 1, X1);
    loadx2(xp, X1, ldact);    // t2+3
  }
}

// ---------------- final FC + length gather ----------------
__global__ void k_final(const f32* __restrict__ h1, const f32* __restrict__ fcw, const f32* __restrict__ fcb,
                        const int* __restrict__ lengths, const int* __restrict__ meta, f32* __restrict__ out){
  int t = blockIdx.x, b = blockIdx.y;
  if (t >= lengths[b]) return;
  __shared__ f32 part[4][64];
  int lane = threadIdx.x & 63, q = threadIdx.x >> 6;
  float acc = 0.f;
  if (lane < 61){
    const f32* wp = fcw + (size_t)lane*512 + q*128;
    const f32* hp = h1 + ((size_t)b*1024 + t)*512 + q*128;
    for (int k=0;k<128;k++) acc = fmaf(hp[k], wp[k], acc);
  }
  part[q][lane] = acc;
  __syncthreads();
  if (q == 0 && lane < 61){
    int row = meta[1 + b] + t;
    out[(size_t)row*61 + lane] = part[0][lane] + part[1][lane] + part[2][lane] + part[3][lane] + fcb[lane];
  }
}

// ---------------- host ----------------
extern "C" void kernel_launch(void* const* d_in, const int* in_sizes, int n_in,
                              void* d_out, int out_size, void* d_ws, size_t ws_size,
                              hipStream_t stream){
  const f32* batch = (const f32*)d_in[0];
  const f32* c1w[4] = {(const f32*)d_in[1],(const f32*)d_in[3],(const f32*)d_in[5],(const f32*)d_in[7]};
  const f32* c1b[4] = {(const f32*)d_in[2],(const f32*)d_in[4],(const f32*)d_in[6],(const f32*)d_in[8]};
  const f32* c2w[4] = {(const f32*)d_in[9],(const f32*)d_in[11],(const f32*)d_in[13],(const f32*)d_in[15]};
  const f32* c2b[4] = {(const f32*)d_in[10],(const f32*)d_in[12],(const f32*)d_in[14],(const f32*)d_in[16]};
  const f32 *bn8g=(const f32*)d_in[17], *bn8b=(const f32*)d_in[18], *bn8m=(const f32*)d_in[19], *bn8v=(const f32*)d_in[20];
  const f32 *bn3g=(const f32*)d_in[21], *bn3b=(const f32*)d_in[22], *bn3m=(const f32*)d_in[23], *bn3v=(const f32*)d_in[24];
  const f32 *fc1w=(const f32*)d_in[25], *fc1b=(const f32*)d_in[26];
  const f32 *g0f_wih=(const f32*)d_in[27], *g0f_whh=(const f32*)d_in[28], *g0f_bih=(const f32*)d_in[29], *g0f_bhh=(const f32*)d_in[30];
  const f32 *g0b_wih=(const f32*)d_in[31], *g0b_whh=(const f32*)d_in[32], *g0b_bih=(const f32*)d_in[33], *g0b_bhh=(const f32*)d_in[34];
  const f32 *g1f_wih=(const f32*)d_in[35], *g1f_whh=(const f32*)d_in[36], *g1f_bih=(const f32*)d_in[37], *g1f_bhh=(const f32*)d_in[38];
  const f32 *g1b_wih=(const f32*)d_in[39], *g1b_whh=(const f32*)d_in[40], *g1b_bih=(const f32*)d_in[41], *g1b_bhh=(const f32*)d_in[42];
  const f32 *fcw=(const f32*)d_in[43], *fcb=(const f32*)d_in[44];
  const int* lengths = (const int*)d_in[45];
  f32* out = (f32*)d_out;

  char* base = (char*)d_ws;
  size_t off = 0;
  auto alloc = [&](size_t bytes)->void*{
    void* p = base + off;
    off += bytes;
    off = (off + 255) & ~(size_t)255;
    return p;
  };

  static const int Hp[4]={510,254,126,62}, Wpp[4]={62,30,14,6};
  static const int K1[4]={4,8,16,32}, S1[4]={1,2,4,8};
  static const int K2[4]={5,3,1,1},  S2[4]={3,2,1,1};
  static const int Ho2[4]={169,126,126,62}, Wo2[4]={20,14,14,6};
  static const int Hr[4]={90,67,67,33}, Wr[4]={9,6,6,2};
  static const int Foff[4]={0,2430,3636,4842};

  f32* r1[4]; for (int i=0;i<4;i++) r1[i] = (f32*)alloc((size_t)16*8*Hp[i]*Wpp[i]*4);
  f32* r2[4]; for (int i=0;i<4;i++) r2[i] = (f32*)alloc((size_t)16*3*Ho2[i]*Wo2[i]*4);
  f32* feats = (f32*)alloc((size_t)16*5040*4);
  f32* rfeat = (f32*)alloc((size_t)16*512*4);
  f32* ydc   = (f32*)alloc((size_t)2*16*768*4);
  int* meta  = (int*)alloc(128*4);
  u16* wfrag = (u16*)alloc((size_t)4*196608*2);
  f32* xwb   = (f32*)alloc((size_t)2*1024*16*768*4);
  f32* h0    = (f32*)alloc((size_t)16*1024*512*4);
  f32* h1p   = (f32*)alloc((size_t)16*1024*512*4);

  k_meta<<<1,64,0,stream>>>(lengths, meta);
  k_wfrag<<<3072,256,0,stream>>>(g0f_whh, g0b_whh, g1f_whh, g1b_whh, wfrag);
  for (int i=0;i<4;i++){
    int np = Hp[i]*Wpp[i];
    k_conv1<<<dim3((np+255)/256,16),256,0,stream>>>(batch, c1w[i], c1b[i], bn8g,bn8b,bn8m,bn8v,
                                                    r1[i], K1[i], S1[i], Hp[i], Wpp[i]);
  }
  for (int i=0;i<4;i++){
    int np = Ho2[i]*Wo2[i];
    k_conv2<<<dim3((np+255)/256,16),256,0,stream>>>(r1[i], c2w[i], c2b[i], bn3g,bn3b,bn3m,bn3v,
                                                    r2[i], K2[i], S2[i], Hp[i], Wpp[i], Ho2[i], Wo2[i]);
  }
  for (int i=0;i<4;i++){
    int tot = 16*3*Hr[i]*Wr[i];
    k_resize<<<(tot+255)/256,256,0,stream>>>(r2[i], meta, feats, Ho2[i], Wo2[i], Hr[i], Wr[i], Foff[i], i);
  }
  k_fc1<<<dim3(16,8),256,0,stream>>>(feats, fc1w, fc1b, rfeat);
  k_ydc<<<96,256,0,stream>>>(rfeat, g0f_wih, g0b_wih, g0f_bih, g0b_bih, ydc);
  k_xw<0><<<dim3(256,12,2),256,0,stream>>>(batch, g0f_wih, g0b_wih, nullptr, nullptr, ydc, g0f_bhh, g0b_bhh, lengths, xwb);
  k_recur<0><<<dim3(8,2),512,0,stream>>>(xwb, wfrag, g0f_bhh, g0b_bhh, lengths, h0);
  k_xw<1><<<dim3(256,12,2),256,0,stream>>>(h0, g1f_wih, g1b_wih, g1f_bih, g1b_bih, nullptr, g1f_bhh, g1b_bhh, lengths, xwb);
  k_recur<1><<<dim3(8,2),512,0,stream>>>(xwb, wfrag, g1f_bhh, g1b_bhh, lengths, h1p);
  k_final<<<dim3(1024,16),256,0,stream>>>(h1p, fcw, fcb, lengths, meta, out);
}

// Round 5
// 3662.463 us; speedup vs baseline: 3.2285x; 1.1643x over previous
//
#include <hip/hip_runtime.h>

typedef float f32;
typedef unsigned int u32;
typedef unsigned short u16;
typedef short s16x8 __attribute__((ext_vector_type(8)));
typedef float f32x4 __attribute__((ext_vector_type(4)));
typedef u32 u32x4 __attribute__((ext_vector_type(4)));

#define S1F (-1.4426950408889634f)   /* -log2(e): r,z pre-scale */
#define S2F ( 2.8853900817779268f)   /* 2*log2(e): n pre-scale  */

__device__ __forceinline__ u16 f2bf(float x){
  u32 u = __float_as_uint(x);
  u32 r = u + 0x7FFFu + ((u >> 16) & 1u);   // round-to-nearest-even
  return (u16)(r >> 16);
}

// ---------------- meta: Lmax, prefix sums, per-branch h_src ----------------
__global__ void k_meta(const int* __restrict__ lengths, int* __restrict__ meta){
  if (threadIdx.x == 0){
    int Lmax = 0;
    for (int b=0;b<16;b++) Lmax = max(Lmax, lengths[b]);
    meta[0] = Lmax;
    int acc = 0;
    for (int b=0;b<16;b++){ meta[1+b] = acc; acc += lengths[b]; }
    meta[17] = acc;
    const int H2s[4] = {169,126,126,62};
    for (int br=0;br<4;br++)
      for (int b=0;b<16;b++){
        double ratio = (double)lengths[b] / (double)Lmax;
        meta[32 + br*16 + b] = (int)((double)H2s[br] * ratio);  // matches np trunc
      }
  }
}

// ---------------- whh -> fragment-ordered bf16 (PRE-SCALED): [set][wave8][tau6][kc8][lane64][j8] ----------------
__global__ void k_wfrag(const f32* __restrict__ w0f, const f32* __restrict__ w0b,
                        const f32* __restrict__ w1f, const f32* __restrict__ w1b,
                        u16* __restrict__ wfrag){
  int idx = blockIdx.x*256 + threadIdx.x;            // < 4*196608
  int set = idx / 196608;
  int e   = idx % 196608;
  int w   = e / 24576;  int r  = e % 24576;
  int tau = r / 4096;   int r2 = r % 4096;
  int kc  = r2 >> 9;    int r3 = r2 & 511;
  int lane= r3 >> 3;    int j  = r3 & 7;
  int g = (tau>>1)*256 + w*32 + (tau&1)*16 + (lane & 15);
  int k = kc*32 + (lane>>4)*8 + j;
  const f32* src = (set==0)? w0f : (set==1)? w0b : (set==2)? w1f : w1b;
  float scale = (tau >= 4) ? S2F : S1F;   // tau 0-3: r,z ; tau 4-5: n
  wfrag[idx] = f2bf(src[g*256 + k] * scale);
}

// ---------------- conv1 (+BN8+ReLU+maxpool2), all 8 out-channels per thread ----------------
__global__ void k_conv1(const f32* __restrict__ x, const f32* __restrict__ w, const f32* __restrict__ cb,
                        const f32* __restrict__ bg, const f32* __restrict__ bbp,
                        const f32* __restrict__ bm, const f32* __restrict__ bv,
                        f32* __restrict__ out, int K, int s, int Hp, int Wp){
  __shared__ f32 wl[8192];
  int b = blockIdx.y;
  int KK = K*K;
  for (int i=threadIdx.x; i<8*KK; i+=256) wl[i] = w[i];
  __syncthreads();
  int idx = blockIdx.x*256 + threadIdx.x;
  int npix = Hp*Wp;
  if (idx >= npix) return;
  int ph = idx / Wp, pw = idx % Wp;
  float mx[8];
  #pragma unroll
  for (int c=0;c<8;c++) mx[c] = -1e30f;
  for (int dy=0; dy<2; ++dy)
  for (int dx=0; dx<2; ++dx){
    const f32* xb = x + ((size_t)b*1024 + (size_t)(ph*2+dy)*s)*128 + (size_t)(pw*2+dx)*s;
    float acc[8];
    #pragma unroll
    for (int c=0;c<8;c++) acc[c] = 0.f;
    for (int kh=0; kh<K; ++kh){
      const f32* xr = xb + kh*128;
      for (int kw=0; kw<K; ++kw){
        float xv = xr[kw];
        #pragma unroll
        for (int c=0;c<8;c++) acc[c] = fmaf(xv, wl[c*KK + kh*K + kw], acc[c]);
      }
    }
    #pragma unroll
    for (int c=0;c<8;c++) mx[c] = fmaxf(mx[c], acc[c]);   // BN scale>0 & ReLU commute with max
  }
  #pragma unroll
  for (int c=0;c<8;c++){
    float scale = bg[c] * rsqrtf(bv[c] + 1e-5f);
    float val = (mx[c] + cb[c] - bm[c]) * scale + bbp[c];
    out[(((size_t)b*8 + c)*Hp + ph)*Wp + pw] = fmaxf(val, 0.f);
  }
}

// ---------------- conv2 (+BN3+ReLU) ----------------
__global__ void k_conv2(const f32* __restrict__ in, const f32* __restrict__ w, const f32* __restrict__ cb,
                        const f32* __restrict__ bg, const f32* __restrict__ bbp,
                        const f32* __restrict__ bm, const f32* __restrict__ bv,
                        f32* __restrict__ out, int K, int s, int Hin, int Win, int Ho, int Wo){
  __shared__ f32 wl[600];
  int b = blockIdx.y;
  int KK = K*K, sz = 24*KK;
  for (int i=threadIdx.x; i<sz; i+=256) wl[i] = w[i];
  __syncthreads();
  int idx = blockIdx.x*256 + threadIdx.x;
  int npix = Ho*Wo;
  if (idx >= npix) return;
  int oh = idx / Wo, ow = idx % Wo;
  float acc[3] = {0.f,0.f,0.f};
  for (int ci=0; ci<8; ++ci){
    const f32* xp = in + (((size_t)b*8 + ci)*Hin + (size_t)oh*s)*Win + (size_t)ow*s;
    for (int kh=0; kh<K; ++kh)
      for (int kw=0; kw<K; ++kw){
        float xv = xp[kh*Win + kw];
        #pragma unroll
        for (int co=0; co<3; ++co) acc[co] = fmaf(xv, wl[(co*8+ci)*KK + kh*K + kw], acc[co]);
      }
  }
  #pragma unroll
  for (int co=0; co<3; ++co){
    float scale = bg[co] * rsqrtf(bv[co] + 1e-5f);
    float val = (acc[co] + cb[co] - bm[co]) * scale + bbp[co];
    out[(((size_t)b*3 + co)*Ho + oh)*Wo + ow] = fmaxf(val, 0.f);
  }
}

// ---------------- per-batch bilinear resize -> flattened feats ----------------
__global__ void k_resize(const f32* __restrict__ src, const int* __restrict__ meta,
                         f32* __restrict__ feats, int H2, int W2, int Ho, int Wo, int off, int br){
  int idx = blockIdx.x*256 + threadIdx.x;
  int per_b = 3*Ho*Wo;
  if (idx >= 16*per_b) return;
  int b = idx / per_b;  int r = idx % per_b;
  int c = r / (Ho*Wo);  int r2 = r % (Ho*Wo);
  int ho = r2 / Wo, wo = r2 % Wo;
  int hs = meta[32 + br*16 + b];
  float cy = ((float)ho + 0.5f) * ((float)hs / (float)Ho) - 0.5f;
  cy = fmaxf(cy, 0.f);
  int him = hs - 1;
  int i0 = min((int)floorf(cy), him);
  int i1 = min(i0 + 1, him);
  float w1 = fminf(fmaxf(cy - (float)i0, 0.f), 1.f);
  float rw = (float)((double)W2 / (double)Wo);
  float cw = ((float)wo + 0.5f) * rw - 0.5f;
  cw = fminf(fmaxf(cw, 0.f), (float)(W2 - 1));
  int j0 = (int)floorf(cw);
  int j1 = min(j0 + 1, W2 - 1);
  float ww = cw - (float)j0;
  const f32* sp = src + (size_t)(b*3 + c) * H2 * W2;
  float v00 = sp[i0*W2 + j0], v01 = sp[i0*W2 + j1];
  float v10 = sp[i1*W2 + j0], v11 = sp[i1*W2 + j1];
  float col0 = v00*(1.f - w1) + v10*w1;
  float col1 = v01*(1.f - w1) + v11*w1;
  feats[(size_t)b*5040 + off + (c*Ho + ho)*Wo + wo] = col0*(1.f - ww) + col1*ww;
}

// ---------------- fc1: rfeat[b][o] = feats[b] . fc1_w[o] + b ----------------
__global__ void k_fc1(const f32* __restrict__ feats, const f32* __restrict__ w,
                      const f32* __restrict__ bias, f32* __restrict__ rfeat){
  int b = blockIdx.x;
  int o0 = blockIdx.y * 64;
  int sub = threadIdx.x & 31, og = threadIdx.x >> 5;
  const f32* fp = feats + (size_t)b*5040;
  for (int oi = og; oi < 64; oi += 8){
    int o = o0 + oi;
    const f32* wp = w + (size_t)o*5040;
    float acc = 0.f;
    for (int k = sub; k < 5040; k += 32) acc = fmaf(fp[k], wp[k], acc);
    #pragma unroll
    for (int m=16; m; m>>=1) acc += __shfl_xor(acc, m, 32);
    if (sub == 0) rfeat[(size_t)b*512 + o] = acc + bias[o];
  }
}

// ---------------- ydc[d][b][g] = bih[g] + rfeat[b] . wih[g, 128:640]  (layer0 time-invariant part) ----------------
__global__ void k_ydc(const f32* __restrict__ rfeat, const f32* __restrict__ wihf, const f32* __restrict__ wihb,
                      const f32* __restrict__ bihf, const f32* __restrict__ bihb, f32* __restrict__ ydc){
  int idx = blockIdx.x*256 + threadIdx.x;   // < 24576
  int d = idx / 12288;  int r = idx % 12288;
  int b = r / 768;      int g = r % 768;
  const f32* wih = d ? wihb : wihf;
  const f32* bih = d ? bihb : bihf;
  const f32* rp = rfeat + (size_t)b*512;
  const f32* wp = wih + (size_t)g*640 + 128;
  float acc = bih[g];
  for (int k=0;k<512;k++) acc = fmaf(rp[k], wp[k], acc);
  ydc[idx] = acc;
}

// ---------------- xW GEMM (bf16 MFMA): xw[dir][t][b][g] ----------------
// rows r = t*16+b (16384), cols g (768). A row gathered (bwd uses rev_idx).
// Folds bhh into r,z cols AND pre-scales gate inputs (r,z: *S1F, n: *S2F).
template<int LAYER>
__global__ __launch_bounds__(256)
void k_xw(const f32* __restrict__ A0, const f32* __restrict__ wihf, const f32* __restrict__ wihb,
          const f32* __restrict__ biasf, const f32* __restrict__ biasb,
          const f32* __restrict__ ydc, const f32* __restrict__ bhf, const f32* __restrict__ bhb,
          const int* __restrict__ lengths, f32* __restrict__ xwbuf){
  constexpr int KT   = (LAYER==0) ? 128 : 512;
  constexpr int WSTR = (LAYER==0) ? 640 : 512;
  int dir = blockIdx.z;
  const f32* wih = dir ? wihb : wihf;
  f32* out = xwbuf + (size_t)dir * 16384 * 768;
  int brow = blockIdx.x * 64, bcol = blockIdx.y * 64;
  __shared__ u32 As[1024], Bs[1024];   // 64 rows x 32 bf16 each
  int tid = threadIdx.x, lane = tid & 63, wid = tid >> 6;
  int rl = tid >> 2, kg = tid & 3;
  int grow = brow + rl;
  int tt = grow >> 4, bb = grow & 15;
  int srct = tt;
  if (dir){ int L = lengths[bb]; srct = (tt < L) ? (L - 1 - tt) : tt; }
  const f32* arow = A0 + ((size_t)bb*1024 + srct) * KT;
  const f32* brp  = wih + (size_t)(bcol + rl) * WSTR;
  int swst = kg ^ ((rl >> 1) & 3);
  u32* adst = &As[rl*16 + swst*4];
  u32* bdst = &Bs[rl*16 + swst*4];
  int r16 = wid*16 + (lane & 15);
  int grp = lane >> 4;
  int aoff = r16*16 + ((grp ^ ((r16 >> 1) & 3)) * 4);
  f32x4 acc[4];
  #pragma unroll
  for (int nt=0; nt<4; ++nt) acc[nt] = (f32x4){0.f,0.f,0.f,0.f};

  for (int kc=0; kc<KT/32; ++kc){
    int k0 = kc*32 + kg*8;
    {
      const f32* ap = arow + k0;
      u32 p0 = (u32)f2bf(ap[0]) | ((u32)f2bf(ap[1])<<16);
      u32 p1 = (u32)f2bf(ap[2]) | ((u32)f2bf(ap[3])<<16);
      u32 p2 = (u32)f2bf(ap[4]) | ((u32)f2bf(ap[5])<<16);
      u32 p3 = (u32)f2bf(ap[6]) | ((u32)f2bf(ap[7])<<16);
      u32x4 v = {p0,p1,p2,p3};
      *(u32x4*)adst = v;
      const f32* bp = brp + k0;
      u32 q0 = (u32)f2bf(bp[0]) | ((u32)f2bf(bp[1])<<16);
      u32 q1 = (u32)f2bf(bp[2]) | ((u32)f2bf(bp[3])<<16);
      u32 q2 = (u32)f2bf(bp[4]) | ((u32)f2bf(bp[5])<<16);
      u32 q3 = (u32)f2bf(bp[6]) | ((u32)f2bf(bp[7])<<16);
      u32x4 u = {q0,q1,q2,q3};
      *(u32x4*)bdst = u;
    }
    __syncthreads();
    s16x8 a = *(const s16x8*)&As[aoff];
    #pragma unroll
    for (int nt=0; nt<4; ++nt){
      int gl = nt*16 + (lane & 15);
      s16x8 bfr = *(const s16x8*)&Bs[gl*16 + ((grp ^ ((gl >> 1) & 3)) * 4)];
      acc[nt] = __builtin_amdgcn_mfma_f32_16x16x32_bf16(a, bfr, acc[nt], 0, 0, 0);
    }
    __syncthreads();
  }
  const f32* bh = dir ? bhb : bhf;
  #pragma unroll
  for (int nt=0; nt<4; ++nt){
    int col = bcol + nt*16 + (lane & 15);
    float bhadd = (col < 512) ? bh[col] : 0.f;
    float scale = (col < 512) ? S1F : S2F;
    #pragma unroll
    for (int q=0; q<4; ++q){
      int row = brow + wid*16 + (lane >> 4)*4 + q;
      float bias;
      if (LAYER == 0) bias = ydc[((size_t)dir*16 + (row & 15))*768 + col];
      else            bias = (dir ? biasb : biasf)[col];
      out[(size_t)row*768 + col] = (acc[nt][q] + bias + bhadd) * scale;
    }
  }
}

// ---------------- GRU recurrence: 2 dirs x 8 batch-groups = 16 blocks ----------------
// Each block: 2 batches, full j (8 waves x 32 j). h_lds = 2 ROWS only (row = l15&1
// broadcast): each ds_read_b128 touches 8 distinct 16B chunks (2 rows x 4 lq), 2-way
// bank alias = free -> h-read LDS cost ~4x lower than 16-row layout. Weights: 5 tiles
// regs + n1 in LDS. X prefetch 2 steps in regs. ONE raw barrier/step.
__device__ __forceinline__ void loadx2(const f32* (&xp)[2], float (&X)[2][6], bool act){
  if (act){
    #pragma unroll
    for (int q=0;q<2;q++){
      const f32* p = xp[q];
      X[q][0]=p[0];   X[q][1]=p[16];     // r (pre-scaled S1F)
      X[q][2]=p[256]; X[q][3]=p[272];    // z (pre-scaled S1F)
      X[q][4]=p[512]; X[q][5]=p[528];    // n (pre-scaled S2F)
    }
  }
  #pragma unroll
  for (int q=0;q<2;q++) xp[q] += 12288;
}

#define GRU_STEP(t_, u_, X_) do { \
  f32x4 a_r0={0.f,0.f,0.f,0.f}, a_r1={0.f,0.f,0.f,0.f}; \
  f32x4 a_z0={0.f,0.f,0.f,0.f}, a_z1={0.f,0.f,0.f,0.f}; \
  f32x4 a_n0={bhn0,bhn0,bhn0,bhn0}, a_n1={bhn1,bhn1,bhn1,bhn1}; \
  _Pragma("unroll") \
  for (int kc=0; kc<8; ++kc){ \
    s16x8 a  = *(const s16x8*)&h_lds[(u_)*512 + hro + kc*32 + lq*8]; \
    s16x8 b5 = *(const s16x8*)&n_lds[(wid*64 + kc*8)*64 + lane*8]; \
    a_r0 = __builtin_amdgcn_mfma_f32_16x16x32_bf16(a, wreg[0][kc], a_r0, 0,0,0); \
    a_r1 = __builtin_amdgcn_mfma_f32_16x16x32_bf16(a, wreg[1][kc], a_r1, 0,0,0); \
    a_z0 = __builtin_amdgcn_mfma_f32_16x16x32_bf16(a, wreg[2][kc], a_z0, 0,0,0); \
    a_z1 = __builtin_amdgcn_mfma_f32_16x16x32_bf16(a, wreg[3][kc], a_z1, 0,0,0); \
    a_n0 = __builtin_amdgcn_mfma_f32_16x16x32_bf16(a, wreg[4][kc], a_n0, 0,0,0); \
    a_n1 = __builtin_amdgcn_mfma_f32_16x16x32_bf16(a, b5,          a_n1, 0,0,0); \
  } \
  if (lq == 0){ \
    _Pragma("unroll") \
    for (int q=0;q<2;q++){ \
      float ar0 = (q==0)? a_r0[0] : a_r0[1];  float ar1 = (q==0)? a_r1[0] : a_r1[1]; \
      float az0 = (q==0)? a_z0[0] : a_z0[1];  float az1 = (q==0)? a_z1[0] : a_z1[1]; \
      float an0 = (q==0)? a_n0[0] : a_n0[1];  float an1 = (q==0)? a_n1[0] : a_n1[1]; \
      float r0 = __builtin_amdgcn_rcpf(1.0f + __builtin_amdgcn_exp2f(X_[q][0] + ar0)); \
      float z0 = __builtin_amdgcn_rcpf(1.0f + __builtin_amdgcn_exp2f(X_[q][2] + az0)); \
      float n0 = fmaf(-2.0f, __builtin_amdgcn_rcpf(__builtin_amdgcn_exp2f(fmaf(r0, an0, X_[q][4])) + 1.0f), 1.0f); \
      float h0v = fmaf(z0, hp[q][0] - n0, n0); \
      hp[q][0] = h0v; \
      float r1 = __builtin_amdgcn_rcpf(1.0f + __builtin_amdgcn_exp2f(X_[q][1] + ar1)); \
      float z1 = __builtin_amdgcn_rcpf(1.0f + __builtin_amdgcn_exp2f(X_[q][3] + az1)); \
      float n1 = fmaf(-2.0f, __builtin_amdgcn_rcpf(__builtin_amdgcn_exp2f(fmaf(r1, an1, X_[q][5])) + 1.0f), 1.0f); \
      float h1v = fmaf(z1, hp[q][1] - n1, n1); \
      hp[q][1] = h1v; \
      u32 ub0 = __float_as_uint(h0v), ub1 = __float_as_uint(h1v); \
      h_lds[((u_)^1)*512 + q*256 + jlo]      = (u16)((ub0 + 0x8000u)>>16); \
      h_lds[((u_)^1)*512 + q*256 + jlo + 16] = (u16)((ub1 + 0x8000u)>>16); \
      if (dir == 0){ \
        hpt[q][0] = h0v; hpt[q][16] = h1v; hpt[q] += 512; \
      } else { \
        int tpos = ((t_) < Lb[q]) ? (Lb[q]-1-(t_)) : (t_); \
        hpt[q][(size_t)tpos*512]      = h0v; \
        hpt[q][(size_t)tpos*512 + 16] = h1v; \
      } \
    } \
  } \
  asm volatile("s_waitcnt lgkmcnt(0)\n\ts_barrier" ::: "memory"); \
} while(0)

template<int LAYER>
__global__ __launch_bounds__(512, 2)
void k_recur(const f32* __restrict__ xw, const u16* __restrict__ wfrag,
             const f32* __restrict__ bhhf, const f32* __restrict__ bhhb,
             const int* __restrict__ lengths, f32* __restrict__ hout){
  __shared__ u16 h_lds[1024];     // 2 bufs x 2 rows x 256 bf16 (broadcast layout)
  __shared__ u16 n_lds[32768];    // 8 waves x 4KB: n1 weight tile, fragment-ordered
  const int dir = blockIdx.y;
  const int b0  = blockIdx.x * 2;           // this block's batches: b0, b0+1
  const int tid = threadIdx.x, lane = tid & 63, wid = tid >> 6;
  const f32* xwd = xw + (size_t)dir * 12582912;
  const f32* bhh = dir ? bhhb : bhhf;
  const u16* wf = wfrag + (size_t)(LAYER*2 + dir) * 196608;

  // tiles tau=0..4 (r0,r1,z0,z1,n0) resident in regs/AGPRs; tau=5 (n1) -> LDS
  s16x8 wreg[5][8];
  #pragma unroll
  for (int tau=0; tau<5; ++tau)
    #pragma unroll
    for (int kc=0; kc<8; ++kc)
      wreg[tau][kc] = *(const s16x8*)(wf + ((size_t)((wid*6+tau)*8 + kc)*64 + lane)*8);
  #pragma unroll
  for (int kc=0; kc<8; ++kc){
    s16x8 v = *(const s16x8*)(wf + ((size_t)((wid*6+5)*8 + kc)*64 + lane)*8);
    *(s16x8*)&n_lds[((size_t)wid*64 + (size_t)kc*8)*64 + (size_t)lane*8] = v;
  }
  ((u32*)h_lds)[tid & 511] = 0;   // 512 u32 = whole 2KB, 512 threads

  const int l15 = lane & 15, lq = lane >> 4;
  const int jlo = (wid << 5) + l15;     // j for tp=0 (tp=1 is +16)
  const int hro = (l15 & 1) * 256;      // broadcast row: only 2 real batches
  const float bhn0 = bhh[512 + jlo] * S2F;
  const float bhn1 = bhh[512 + jlo + 16] * S2F;
  int Lb[2] = { lengths[b0], lengths[b0+1] };
  float hp[2][2] = {{0.f,0.f},{0.f,0.f}};   // [q][tp]

  const bool ldact = (lq == 0);
  const f32* xp[2];
  #pragma unroll
  for (int q=0;q<2;q++) xp[q] = xwd + (size_t)(b0+q)*768 + jlo;
  f32* hpt[2];
  #pragma unroll
  for (int q=0;q<2;q++) hpt[q] = hout + (size_t)(b0+q)*1024*512 + dir*256 + jlo;

  float X0[2][6], X1[2][6];
  loadx2(xp, X0, ldact);      // t=0
  loadx2(xp, X1, ldact);      // t=1
  __syncthreads();

  for (int t2=0; t2<1024; t2+=2){
    GRU_STEP(t2,   0, X0);
    loadx2(xp, X0, ldact);    // t2+2 (last iter overreads <=96KB into next ws region: safe)
    GRU_STEP(t2+1, 1, X1);
    loadx2(xp, X1, ldact);    // t2+3
  }
}

// ---------------- final FC + length gather ----------------
__global__ void k_final(const f32* __restrict__ h1, const f32* __restrict__ fcw, const f32* __restrict__ fcb,
                        const int* __restrict__ lengths, const int* __restrict__ meta, f32* __restrict__ out){
  int t = blockIdx.x, b = blockIdx.y;
  if (t >= lengths[b]) return;
  __shared__ f32 part[4][64];
  int lane = threadIdx.x & 63, q = threadIdx.x >> 6;
  float acc = 0.f;
  if (lane < 61){
    const f32* wp = fcw + (size_t)lane*512 + q*128;
    const f32* hp = h1 + ((size_t)b*1024 + t)*512 + q*128;
    for (int k=0;k<128;k++) acc = fmaf(hp[k], wp[k], acc);
  }
  part[q][lane] = acc;
  __syncthreads();
  if (q == 0 && lane < 61){
    int row = meta[1 + b] + t;
    out[(size_t)row*61 + lane] = part[0][lane] + part[1][lane] + part[2][lane] + part[3][lane] + fcb[lane];
  }
}

// ---------------- host ----------------
extern "C" void kernel_launch(void* const* d_in, const int* in_sizes, int n_in,
                              void* d_out, int out_size, void* d_ws, size_t ws_size,
                              hipStream_t stream){
  const f32* batch = (const f32*)d_in[0];
  const f32* c1w[4] = {(const f32*)d_in[1],(const f32*)d_in[3],(const f32*)d_in[5],(const f32*)d_in[7]};
  const f32* c1b[4] = {(const f32*)d_in[2],(const f32*)d_in[4],(const f32*)d_in[6],(const f32*)d_in[8]};
  const f32* c2w[4] = {(const f32*)d_in[9],(const f32*)d_in[11],(const f32*)d_in[13],(const f32*)d_in[15]};
  const f32* c2b[4] = {(const f32*)d_in[10],(const f32*)d_in[12],(const f32*)d_in[14],(const f32*)d_in[16]};
  const f32 *bn8g=(const f32*)d_in[17], *bn8b=(const f32*)d_in[18], *bn8m=(const f32*)d_in[19], *bn8v=(const f32*)d_in[20];
  const f32 *bn3g=(const f32*)d_in[21], *bn3b=(const f32*)d_in[22], *bn3m=(const f32*)d_in[23], *bn3v=(const f32*)d_in[24];
  const f32 *fc1w=(const f32*)d_in[25], *fc1b=(const f32*)d_in[26];
  const f32 *g0f_wih=(const f32*)d_in[27], *g0f_whh=(const f32*)d_in[28], *g0f_bih=(const f32*)d_in[29], *g0f_bhh=(const f32*)d_in[30];
  const f32 *g0b_wih=(const f32*)d_in[31], *g0b_whh=(const f32*)d_in[32], *g0b_bih=(const f32*)d_in[33], *g0b_bhh=(const f32*)d_in[34];
  const f32 *g1f_wih=(const f32*)d_in[35], *g1f_whh=(const f32*)d_in[36], *g1f_bih=(const f32*)d_in[37], *g1f_bhh=(const f32*)d_in[38];
  const f32 *g1b_wih=(const f32*)d_in[39], *g1b_whh=(const f32*)d_in[40], *g1b_bih=(const f32*)d_in[41], *g1b_bhh=(const f32*)d_in[42];
  const f32 *fcw=(const f32*)d_in[43], *fcb=(const f32*)d_in[44];
  const int* lengths = (const int*)d_in[45];
  f32* out = (f32*)d_out;

  char* base = (char*)d_ws;
  size_t off = 0;
  auto alloc = [&](size_t bytes)->void*{
    void* p = base + off;
    off += bytes;
    off = (off + 255) & ~(size_t)255;
    return p;
  };

  static const int Hp[4]={510,254,126,62}, Wpp[4]={62,30,14,6};
  static const int K1[4]={4,8,16,32}, S1[4]={1,2,4,8};
  static const int K2[4]={5,3,1,1},  S2[4]={3,2,1,1};
  static const int Ho2[4]={169,126,126,62}, Wo2[4]={20,14,14,6};
  static const int Hr[4]={90,67,67,33}, Wr[4]={9,6,6,2};
  static const int Foff[4]={0,2430,3636,4842};

  f32* r1[4]; for (int i=0;i<4;i++) r1[i] = (f32*)alloc((size_t)16*8*Hp[i]*Wpp[i]*4);
  f32* r2[4]; for (int i=0;i<4;i++) r2[i] = (f32*)alloc((size_t)16*3*Ho2[i]*Wo2[i]*4);
  f32* feats = (f32*)alloc((size_t)16*5040*4);
  f32* rfeat = (f32*)alloc((size_t)16*512*4);
  f32* ydc   = (f32*)alloc((size_t)2*16*768*4);
  int* meta  = (int*)alloc(128*4);
  u16* wfrag = (u16*)alloc((size_t)4*196608*2);
  f32* xwb   = (f32*)alloc((size_t)2*1024*16*768*4);
  f32* h0    = (f32*)alloc((size_t)16*1024*512*4);
  f32* h1p   = (f32*)alloc((size_t)16*1024*512*4);

  k_meta<<<1,64,0,stream>>>(lengths, meta);
  k_wfrag<<<3072,256,0,stream>>>(g0f_whh, g0b_whh, g1f_whh, g1b_whh, wfrag);
  for (int i=0;i<4;i++){
    int np = Hp[i]*Wpp[i];
    k_conv1<<<dim3((np+255)/256,16),256,0,stream>>>(batch, c1w[i], c1b[i], bn8g,bn8b,bn8m,bn8v,
                                                    r1[i], K1[i], S1[i], Hp[i], Wpp[i]);
  }
  for (int i=0;i<4;i++){
    int np = Ho2[i]*Wo2[i];
    k_conv2<<<dim3((np+255)/256,16),256,0,stream>>>(r1[i], c2w[i], c2b[i], bn3g,bn3b,bn3m,bn3v,
                                                    r2[i], K2[i], S2[i], Hp[i], Wpp[i], Ho2[i], Wo2[i]);
  }
  for (int i=0;i<4;i++){
    int tot = 16*3*Hr[i]*Wr[i];
    k_resize<<<(tot+255)/256,256,0,stream>>>(r2[i], meta, feats, Ho2[i], Wo2[i], Hr[i], Wr[i], Foff[i], i);
  }
  k_fc1<<<dim3(16,8),256,0,stream>>>(feats, fc1w, fc1b, rfeat);
  k_ydc<<<96,256,0,stream>>>(rfeat, g0f_wih, g0b_wih, g0f_bih, g0b_bih, ydc);
  k_xw<0><<<dim3(256,12,2),256,0,stream>>>(batch, g0f_wih, g0b_wih, nullptr, nullptr, ydc, g0f_bhh, g0b_bhh, lengths, xwb);
  k_recur<0><<<dim3(8,2),512,0,stream>>>(xwb, wfrag, g0f_bhh, g0b_bhh, lengths, h0);
  k_xw<1><<<dim3(256,12,2),256,0,stream>>>(h0, g1f_wih, g1b_wih, g1f_bih, g1b_bih, nullptr, g1f_bhh, g1b_bhh, lengths, xwb);
  k_recur<1><<<dim3(8,2),512,0,stream>>>(xwb, wfrag, g1f_bhh, g1b_bhh, lengths, h1p);
  k_final<<<dim3(1024,16),256,0,stream>>>(h1p, fcw, fcb, lengths, meta, out);
}

// Round 6
// 2885.136 us; speedup vs baseline: 4.0984x; 1.2694x over previous
//
#include <hip/hip_runtime.h>

typedef float f32;
typedef unsigned int u32;
typedef unsigned short u16;
typedef short s16x8 __attribute__((ext_vector_type(8)));
typedef float f32x4 __attribute__((ext_vector_type(4)));
typedef u32 u32x4 __attribute__((ext_vector_type(4)));

#define S1F (-1.4426950408889634f)   /* -log2(e): r,z pre-scale */
#define S2F ( 2.8853900817779268f)   /* 2*log2(e): n pre-scale  */

__device__ __forceinline__ u16 f2bf(float x){
  u32 u = __float_as_uint(x);
  u32 r = u + 0x7FFFu + ((u >> 16) & 1u);   // round-to-nearest-even
  return (u16)(r >> 16);
}

// ---------------- meta: Lmax, prefix sums, per-branch h_src ----------------
__global__ void k_meta(const int* __restrict__ lengths, int* __restrict__ meta){
  if (threadIdx.x == 0){
    int Lmax = 0;
    for (int b=0;b<16;b++) Lmax = max(Lmax, lengths[b]);
    meta[0] = Lmax;
    int acc = 0;
    for (int b=0;b<16;b++){ meta[1+b] = acc; acc += lengths[b]; }
    meta[17] = acc;
    const int H2s[4] = {169,126,126,62};
    for (int br=0;br<4;br++)
      for (int b=0;b<16;b++){
        double ratio = (double)lengths[b] / (double)Lmax;
        meta[32 + br*16 + b] = (int)((double)H2s[br] * ratio);  // matches np trunc
      }
  }
}

// ---------------- whh -> fragment-ordered bf16 (PRE-SCALED): [set][wave8][tau6][kc8][lane64][j8] ----------------
__global__ void k_wfrag(const f32* __restrict__ w0f, const f32* __restrict__ w0b,
                        const f32* __restrict__ w1f, const f32* __restrict__ w1b,
                        u16* __restrict__ wfrag){
  int idx = blockIdx.x*256 + threadIdx.x;            // < 4*196608
  int set = idx / 196608;
  int e   = idx % 196608;
  int w   = e / 24576;  int r  = e % 24576;
  int tau = r / 4096;   int r2 = r % 4096;
  int kc  = r2 >> 9;    int r3 = r2 & 511;
  int lane= r3 >> 3;    int j  = r3 & 7;
  int g = (tau>>1)*256 + w*32 + (tau&1)*16 + (lane & 15);
  int k = kc*32 + (lane>>4)*8 + j;
  const f32* src = (set==0)? w0f : (set==1)? w0b : (set==2)? w1f : w1b;
  float scale = (tau >= 4) ? S2F : S1F;   // tau 0-3: r,z ; tau 4-5: n
  wfrag[idx] = f2bf(src[g*256 + k] * scale);
}

// ---------------- conv1 (+BN8+ReLU+maxpool2), all 8 out-channels per thread ----------------
__global__ void k_conv1(const f32* __restrict__ x, const f32* __restrict__ w, const f32* __restrict__ cb,
                        const f32* __restrict__ bg, const f32* __restrict__ bbp,
                        const f32* __restrict__ bm, const f32* __restrict__ bv,
                        f32* __restrict__ out, int K, int s, int Hp, int Wp){
  __shared__ f32 wl[8192];
  int b = blockIdx.y;
  int KK = K*K;
  for (int i=threadIdx.x; i<8*KK; i+=256) wl[i] = w[i];
  __syncthreads();
  int idx = blockIdx.x*256 + threadIdx.x;
  int npix = Hp*Wp;
  if (idx >= npix) return;
  int ph = idx / Wp, pw = idx % Wp;
  float mx[8];
  #pragma unroll
  for (int c=0;c<8;c++) mx[c] = -1e30f;
  for (int dy=0; dy<2; ++dy)
  for (int dx=0; dx<2; ++dx){
    const f32* xb = x + ((size_t)b*1024 + (size_t)(ph*2+dy)*s)*128 + (size_t)(pw*2+dx)*s;
    float acc[8];
    #pragma unroll
    for (int c=0;c<8;c++) acc[c] = 0.f;
    for (int kh=0; kh<K; ++kh){
      const f32* xr = xb + kh*128;
      for (int kw=0; kw<K; ++kw){
        float xv = xr[kw];
        #pragma unroll
        for (int c=0;c<8;c++) acc[c] = fmaf(xv, wl[c*KK + kh*K + kw], acc[c]);
      }
    }
    #pragma unroll
    for (int c=0;c<8;c++) mx[c] = fmaxf(mx[c], acc[c]);   // BN scale>0 & ReLU commute with max
  }
  #pragma unroll
  for (int c=0;c<8;c++){
    float scale = bg[c] * rsqrtf(bv[c] + 1e-5f);
    float val = (mx[c] + cb[c] - bm[c]) * scale + bbp[c];
    out[(((size_t)b*8 + c)*Hp + ph)*Wp + pw] = fmaxf(val, 0.f);
  }
}

// ---------------- conv2 (+BN3+ReLU) ----------------
__global__ void k_conv2(const f32* __restrict__ in, const f32* __restrict__ w, const f32* __restrict__ cb,
                        const f32* __restrict__ bg, const f32* __restrict__ bbp,
                        const f32* __restrict__ bm, const f32* __restrict__ bv,
                        f32* __restrict__ out, int K, int s, int Hin, int Win, int Ho, int Wo){
  __shared__ f32 wl[600];
  int b = blockIdx.y;
  int KK = K*K, sz = 24*KK;
  for (int i=threadIdx.x; i<sz; i+=256) wl[i] = w[i];
  __syncthreads();
  int idx = blockIdx.x*256 + threadIdx.x;
  int npix = Ho*Wo;
  if (idx >= npix) return;
  int oh = idx / Wo, ow = idx % Wo;
  float acc[3] = {0.f,0.f,0.f};
  for (int ci=0; ci<8; ++ci){
    const f32* xp = in + (((size_t)b*8 + ci)*Hin + (size_t)oh*s)*Win + (size_t)ow*s;
    for (int kh=0; kh<K; ++kh)
      for (int kw=0; kw<K; ++kw){
        float xv = xp[kh*Win + kw];
        #pragma unroll
        for (int co=0; co<3; ++co) acc[co] = fmaf(xv, wl[(co*8+ci)*KK + kh*K + kw], acc[co]);
      }
  }
  #pragma unroll
  for (int co=0; co<3; ++co){
    float scale = bg[co] * rsqrtf(bv[co] + 1e-5f);
    float val = (acc[co] + cb[co] - bm[co]) * scale + bbp[co];
    out[(((size_t)b*3 + co)*Ho + oh)*Wo + ow] = fmaxf(val, 0.f);
  }
}

// ---------------- per-batch bilinear resize -> flattened feats ----------------
__global__ void k_resize(const f32* __restrict__ src, const int* __restrict__ meta,
                         f32* __restrict__ feats, int H2, int W2, int Ho, int Wo, int off, int br){
  int idx = blockIdx.x*256 + threadIdx.x;
  int per_b = 3*Ho*Wo;
  if (idx >= 16*per_b) return;
  int b = idx / per_b;  int r = idx % per_b;
  int c = r / (Ho*Wo);  int r2 = r % (Ho*Wo);
  int ho = r2 / Wo, wo = r2 % Wo;
  int hs = meta[32 + br*16 + b];
  float cy = ((float)ho + 0.5f) * ((float)hs / (float)Ho) - 0.5f;
  cy = fmaxf(cy, 0.f);
  int him = hs - 1;
  int i0 = min((int)floorf(cy), him);
  int i1 = min(i0 + 1, him);
  float w1 = fminf(fmaxf(cy - (float)i0, 0.f), 1.f);
  float rw = (float)((double)W2 / (double)Wo);
  float cw = ((float)wo + 0.5f) * rw - 0.5f;
  cw = fminf(fmaxf(cw, 0.f), (float)(W2 - 1));
  int j0 = (int)floorf(cw);
  int j1 = min(j0 + 1, W2 - 1);
  float ww = cw - (float)j0;
  const f32* sp = src + (size_t)(b*3 + c) * H2 * W2;
  float v00 = sp[i0*W2 + j0], v01 = sp[i0*W2 + j1];
  float v10 = sp[i1*W2 + j0], v11 = sp[i1*W2 + j1];
  float col0 = v00*(1.f - w1) + v10*w1;
  float col1 = v01*(1.f - w1) + v11*w1;
  feats[(size_t)b*5040 + off + (c*Ho + ho)*Wo + wo] = col0*(1.f - ww) + col1*ww;
}

// ---------------- fc1: rfeat[b][o] = feats[b] . fc1_w[o] + b ----------------
__global__ void k_fc1(const f32* __restrict__ feats, const f32* __restrict__ w,
                      const f32* __restrict__ bias, f32* __restrict__ rfeat){
  int b = blockIdx.x;
  int o0 = blockIdx.y * 64;
  int sub = threadIdx.x & 31, og = threadIdx.x >> 5;
  const f32* fp = feats + (size_t)b*5040;
  for (int oi = og; oi < 64; oi += 8){
    int o = o0 + oi;
    const f32* wp = w + (size_t)o*5040;
    float acc = 0.f;
    for (int k = sub; k < 5040; k += 32) acc = fmaf(fp[k], wp[k], acc);
    #pragma unroll
    for (int m=16; m; m>>=1) acc += __shfl_xor(acc, m, 32);
    if (sub == 0) rfeat[(size_t)b*512 + o] = acc + bias[o];
  }
}

// ---------------- ydc[d][b][g] = bih[g] + rfeat[b] . wih[g, 128:640]  (layer0 time-invariant part) ----------------
__global__ void k_ydc(const f32* __restrict__ rfeat, const f32* __restrict__ wihf, const f32* __restrict__ wihb,
                      const f32* __restrict__ bihf, const f32* __restrict__ bihb, f32* __restrict__ ydc){
  int idx = blockIdx.x*256 + threadIdx.x;   // < 24576
  int d = idx / 12288;  int r = idx % 12288;
  int b = r / 768;      int g = r % 768;
  const f32* wih = d ? wihb : wihf;
  const f32* bih = d ? bihb : bihf;
  const f32* rp = rfeat + (size_t)b*512;
  const f32* wp = wih + (size_t)g*640 + 128;
  float acc = bih[g];
  for (int k=0;k<512;k++) acc = fmaf(rp[k], wp[k], acc);
  ydc[idx] = acc;
}

// ---------------- xW GEMM (bf16 MFMA): xw[dir][t][b][g] ----------------
// rows r = t*16+b (16384), cols g (768). A row gathered (bwd uses rev_idx).
// Folds bhh into r,z cols AND pre-scales gate inputs (r,z: *S1F, n: *S2F).
template<int LAYER>
__global__ __launch_bounds__(256)
void k_xw(const f32* __restrict__ A0, const f32* __restrict__ wihf, const f32* __restrict__ wihb,
          const f32* __restrict__ biasf, const f32* __restrict__ biasb,
          const f32* __restrict__ ydc, const f32* __restrict__ bhf, const f32* __restrict__ bhb,
          const int* __restrict__ lengths, f32* __restrict__ xwbuf){
  constexpr int KT   = (LAYER==0) ? 128 : 512;
  constexpr int WSTR = (LAYER==0) ? 640 : 512;
  int dir = blockIdx.z;
  const f32* wih = dir ? wihb : wihf;
  f32* out = xwbuf + (size_t)dir * 16384 * 768;
  int brow = blockIdx.x * 64, bcol = blockIdx.y * 64;
  __shared__ u32 As[1024], Bs[1024];   // 64 rows x 32 bf16 each
  int tid = threadIdx.x, lane = tid & 63, wid = tid >> 6;
  int rl = tid >> 2, kg = tid & 3;
  int grow = brow + rl;
  int tt = grow >> 4, bb = grow & 15;
  int srct = tt;
  if (dir){ int L = lengths[bb]; srct = (tt < L) ? (L - 1 - tt) : tt; }
  const f32* arow = A0 + ((size_t)bb*1024 + srct) * KT;
  const f32* brp  = wih + (size_t)(bcol + rl) * WSTR;
  int swst = kg ^ ((rl >> 1) & 3);
  u32* adst = &As[rl*16 + swst*4];
  u32* bdst = &Bs[rl*16 + swst*4];
  int r16 = wid*16 + (lane & 15);
  int grp = lane >> 4;
  int aoff = r16*16 + ((grp ^ ((r16 >> 1) & 3)) * 4);
  f32x4 acc[4];
  #pragma unroll
  for (int nt=0; nt<4; ++nt) acc[nt] = (f32x4){0.f,0.f,0.f,0.f};

  for (int kc=0; kc<KT/32; ++kc){
    int k0 = kc*32 + kg*8;
    {
      f32x4 av0 = *(const f32x4*)(arow + k0);
      f32x4 av1 = *(const f32x4*)(arow + k0 + 4);
      u32 p0 = (u32)f2bf(av0[0]) | ((u32)f2bf(av0[1])<<16);
      u32 p1 = (u32)f2bf(av0[2]) | ((u32)f2bf(av0[3])<<16);
      u32 p2 = (u32)f2bf(av1[0]) | ((u32)f2bf(av1[1])<<16);
      u32 p3 = (u32)f2bf(av1[2]) | ((u32)f2bf(av1[3])<<16);
      u32x4 v = {p0,p1,p2,p3};
      *(u32x4*)adst = v;
      f32x4 bv0 = *(const f32x4*)(brp + k0);
      f32x4 bv1 = *(const f32x4*)(brp + k0 + 4);
      u32 q0 = (u32)f2bf(bv0[0]) | ((u32)f2bf(bv0[1])<<16);
      u32 q1 = (u32)f2bf(bv0[2]) | ((u32)f2bf(bv0[3])<<16);
      u32 q2 = (u32)f2bf(bv1[0]) | ((u32)f2bf(bv1[1])<<16);
      u32 q3 = (u32)f2bf(bv1[2]) | ((u32)f2bf(bv1[3])<<16);
      u32x4 u = {q0,q1,q2,q3};
      *(u32x4*)bdst = u;
    }
    __syncthreads();
    s16x8 a = *(const s16x8*)&As[aoff];
    #pragma unroll
    for (int nt=0; nt<4; ++nt){
      int gl = nt*16 + (lane & 15);
      s16x8 bfr = *(const s16x8*)&Bs[gl*16 + ((grp ^ ((gl >> 1) & 3)) * 4)];
      acc[nt] = __builtin_amdgcn_mfma_f32_16x16x32_bf16(a, bfr, acc[nt], 0, 0, 0);
    }
    __syncthreads();
  }
  const f32* bh = dir ? bhb : bhf;
  #pragma unroll
  for (int nt=0; nt<4; ++nt){
    int col = bcol + nt*16 + (lane & 15);
    float bhadd = (col < 512) ? bh[col] : 0.f;
    float scale = (col < 512) ? S1F : S2F;
    #pragma unroll
    for (int q=0; q<4; ++q){
      int row = brow + wid*16 + (lane >> 4)*4 + q;
      float bias;
      if (LAYER == 0) bias = ydc[((size_t)dir*16 + (row & 15))*768 + col];
      else            bias = (dir ? biasb : biasf)[col];
      out[(size_t)row*768 + col] = (acc[nt][q] + bias + bhadd) * scale;
    }
  }
}

// ---------------- GRU recurrence: 2 dirs x 8 batch-groups = 16 blocks ----------------
// Each block: 2 batches (h rows broadcast [0,1,0,1,..]), 8 waves x 32 j. ALL 6 weight
// tiles in registers (192 regs; gate-spread freed the pressure). Gate phase spread
// across ALL lanes: lane (l15,lq) owns one h value (q=lq&1, tp=lq>>1) -> ~20 VALU
// parallel instead of ~48 serial in 1/4 of lanes. h_lds row stride 288 u16 (576B ==
// 64 mod 128) -> row0 banks 0-15, row1 banks 16-31: zero aliasing. One barrier/step.
#define GRU_STEP(t_, u_, X_) do { \
  f32x4 a_r0={0.f,0.f,0.f,0.f}, a_r1={0.f,0.f,0.f,0.f}; \
  f32x4 a_z0={0.f,0.f,0.f,0.f}, a_z1={0.f,0.f,0.f,0.f}; \
  f32x4 a_n0={bhn0,bhn0,bhn0,bhn0}, a_n1={bhn1,bhn1,bhn1,bhn1}; \
  _Pragma("unroll") \
  for (int kc=0; kc<8; ++kc){ \
    s16x8 a = *(const s16x8*)&h_lds[(u_)*576 + hro + kc*32 + lq*8]; \
    a_r0 = __builtin_amdgcn_mfma_f32_16x16x32_bf16(a, wreg[0][kc], a_r0, 0,0,0); \
    a_r1 = __builtin_amdgcn_mfma_f32_16x16x32_bf16(a, wreg[1][kc], a_r1, 0,0,0); \
    a_z0 = __builtin_amdgcn_mfma_f32_16x16x32_bf16(a, wreg[2][kc], a_z0, 0,0,0); \
    a_z1 = __builtin_amdgcn_mfma_f32_16x16x32_bf16(a, wreg[3][kc], a_z1, 0,0,0); \
    a_n0 = __builtin_amdgcn_mfma_f32_16x16x32_bf16(a, wreg[4][kc], a_n0, 0,0,0); \
    a_n1 = __builtin_amdgcn_mfma_f32_16x16x32_bf16(a, wreg[5][kc], a_n1, 0,0,0); \
  } \
  { \
    float ar0 = qi ? a_r0[1] : a_r0[0], ar1 = qi ? a_r1[1] : a_r1[0]; \
    float az0 = qi ? a_z0[1] : a_z0[0], az1 = qi ? a_z1[1] : a_z1[0]; \
    float an0 = qi ? a_n0[1] : a_n0[0], an1 = qi ? a_n1[1] : a_n1[0]; \
    float ar = tpi ? ar1 : ar0; \
    float az = tpi ? az1 : az0; \
    float an = tpi ? an1 : an0; \
    float r = __builtin_amdgcn_rcpf(1.0f + __builtin_amdgcn_exp2f(X_[0] + ar)); \
    float z = __builtin_amdgcn_rcpf(1.0f + __builtin_amdgcn_exp2f(X_[1] + az)); \
    float n = fmaf(-2.0f, __builtin_amdgcn_rcpf(__builtin_amdgcn_exp2f(fmaf(r, an, X_[2])) + 1.0f), 1.0f); \
    float hv = fmaf(z, hp - n, n); \
    hp = hv; \
    u32 ub = __float_as_uint(hv); \
    h_lds[((u_)^1)*576 + qi*288 + jme] = (u16)((ub + 0x8000u)>>16); \
    if (dir == 0){ *hpt = hv; hpt += 512; } \
    else { int tpos = ((t_) < Lq) ? (Lq-1-(t_)) : (t_); hpt[(size_t)tpos*512] = hv; } \
  } \
  asm volatile("s_waitcnt lgkmcnt(0)\n\ts_barrier" ::: "memory"); \
} while(0)

template<int LAYER>
__global__ __launch_bounds__(512, 2)
void k_recur(const f32* __restrict__ xw, const u16* __restrict__ wfrag,
             const f32* __restrict__ bhhf, const f32* __restrict__ bhhb,
             const int* __restrict__ lengths, f32* __restrict__ hout){
  __shared__ u16 h_lds[1152];     // 2 bufs x 2 rows x 288 u16 (padded: rows hit disjoint banks)
  const int dir = blockIdx.y;
  const int b0  = blockIdx.x * 2;           // this block's batches: b0, b0+1
  const int tid = threadIdx.x, lane = tid & 63, wid = tid >> 6;
  const f32* xwd = xw + (size_t)dir * 12582912;
  const f32* bhh = dir ? bhhb : bhhf;
  const u16* wf = wfrag + (size_t)(LAYER*2 + dir) * 196608;

  // all 6 tiles (r0,r1,z0,z1,n0,n1) resident in regs/AGPRs
  s16x8 wreg[6][8];
  #pragma unroll
  for (int tau=0; tau<6; ++tau)
    #pragma unroll
    for (int kc=0; kc<8; ++kc)
      wreg[tau][kc] = *(const s16x8*)(wf + ((size_t)((wid*6+tau)*8 + kc)*64 + lane)*8);
  if (tid < 576) ((u32*)h_lds)[tid] = 0;

  const int l15 = lane & 15, lq = lane >> 4;
  const int jlo = (wid << 5) + l15;     // col for tp=0 tiles (tp=1 is +16)
  const int hro = (l15 & 1) * 288;      // broadcast row: batches alternate [0,1,..]
  const int qi  = lq & 1;               // this lane's batch
  const int tpi = lq >> 1;              // this lane's j-half
  const int jme = jlo + tpi*16;         // this lane's j
  const float bhn0 = bhh[512 + jlo] * S2F;
  const float bhn1 = bhh[512 + jlo + 16] * S2F;
  const int Lq = lengths[b0 + qi];
  float hp = 0.f;

  const f32* xp = xwd + (size_t)(b0+qi)*768 + jme;
  f32* hpt = hout + (size_t)(b0+qi)*1024*512 + dir*256 + jme;

  float X0[3], X1[3];
  X0[0]=xp[0]; X0[1]=xp[256]; X0[2]=xp[512]; xp += 12288;   // t=0
  X1[0]=xp[0]; X1[1]=xp[256]; X1[2]=xp[512]; xp += 12288;   // t=1
  __syncthreads();

  for (int t2=0; t2<1024; t2+=2){
    GRU_STEP(t2,   0, X0);
    X0[0]=xp[0]; X0[1]=xp[256]; X0[2]=xp[512]; xp += 12288;  // t2+2 (tail overread: ws-safe)
    GRU_STEP(t2+1, 1, X1);
    X1[0]=xp[0]; X1[1]=xp[256]; X1[2]=xp[512]; xp += 12288;  // t2+3
  }
}

// ---------------- final FC + length gather ----------------
__global__ void k_final(const f32* __restrict__ h1, const f32* __restrict__ fcw, const f32* __restrict__ fcb,
                        const int* __restrict__ lengths, const int* __restrict__ meta, f32* __restrict__ out){
  int t = blockIdx.x, b = blockIdx.y;
  if (t >= lengths[b]) return;
  __shared__ f32 part[4][64];
  int lane = threadIdx.x & 63, q = threadIdx.x >> 6;
  float acc = 0.f;
  if (lane < 61){
    const f32* wp = fcw + (size_t)lane*512 + q*128;
    const f32* hp = h1 + ((size_t)b*1024 + t)*512 + q*128;
    for (int k=0;k<128;k++) acc = fmaf(hp[k], wp[k], acc);
  }
  part[q][lane] = acc;
  __syncthreads();
  if (q == 0 && lane < 61){
    int row = meta[1 + b] + t;
    out[(size_t)row*61 + lane] = part[0][lane] + part[1][lane] + part[2][lane] + part[3][lane] + fcb[lane];
  }
}

// ---------------- host ----------------
extern "C" void kernel_launch(void* const* d_in, const int* in_sizes, int n_in,
                              void* d_out, int out_size, void* d_ws, size_t ws_size,
                              hipStream_t stream){
  const f32* batch = (const f32*)d_in[0];
  const f32* c1w[4] = {(const f32*)d_in[1],(const f32*)d_in[3],(const f32*)d_in[5],(const f32*)d_in[7]};
  const f32* c1b[4] = {(const f32*)d_in[2],(const f32*)d_in[4],(const f32*)d_in[6],(const f32*)d_in[8]};
  const f32* c2w[4] = {(const f32*)d_in[9],(const f32*)d_in[11],(const f32*)d_in[13],(const f32*)d_in[15]};
  const f32* c2b[4] = {(const f32*)d_in[10],(const f32*)d_in[12],(const f32*)d_in[14],(const f32*)d_in[16]};
  const f32 *bn8g=(const f32*)d_in[17], *bn8b=(const f32*)d_in[18], *bn8m=(const f32*)d_in[19], *bn8v=(const f32*)d_in[20];
  const f32 *bn3g=(const f32*)d_in[21], *bn3b=(const f32*)d_in[22], *bn3m=(const f32*)d_in[23], *bn3v=(const f32*)d_in[24];
  const f32 *fc1w=(const f32*)d_in[25], *fc1b=(const f32*)d_in[26];
  const f32 *g0f_wih=(const f32*)d_in[27], *g0f_whh=(const f32*)d_in[28], *g0f_bih=(const f32*)d_in[29], *g0f_bhh=(const f32*)d_in[30];
  const f32 *g0b_wih=(const f32*)d_in[31], *g0b_whh=(const f32*)d_in[32], *g0b_bih=(const f32*)d_in[33], *g0b_bhh=(const f32*)d_in[34];
  const f32 *g1f_wih=(const f32*)d_in[35], *g1f_whh=(const f32*)d_in[36], *g1f_bih=(const f32*)d_in[37], *g1f_bhh=(const f32*)d_in[38];
  const f32 *g1b_wih=(const f32*)d_in[39], *g1b_whh=(const f32*)d_in[40], *g1b_bih=(const f32*)d_in[41], *g1b_bhh=(const f32*)d_in[42];
  const f32 *fcw=(const f32*)d_in[43], *fcb=(const f32*)d_in[44];
  const int* lengths = (const int*)d_in[45];
  f32* out = (f32*)d_out;

  char* base = (char*)d_ws;
  size_t off = 0;
  auto alloc = [&](size_t bytes)->void*{
    void* p = base + off;
    off += bytes;
    off = (off + 255) & ~(size_t)255;
    return p;
  };

  static const int Hp[4]={510,254,126,62}, Wpp[4]={62,30,14,6};
  static const int K1[4]={4,8,16,32}, S1[4]={1,2,4,8};
  static const int K2[4]={5,3,1,1},  S2[4]={3,2,1,1};
  static const int Ho2[4]={169,126,126,62}, Wo2[4]={20,14,14,6};
  static const int Hr[4]={90,67,67,33}, Wr[4]={9,6,6,2};
  static const int Foff[4]={0,2430,3636,4842};

  f32* r1[4]; for (int i=0;i<4;i++) r1[i] = (f32*)alloc((size_t)16*8*Hp[i]*Wpp[i]*4);
  f32* r2[4]; for (int i=0;i<4;i++) r2[i] = (f32*)alloc((size_t)16*3*Ho2[i]*Wo2[i]*4);
  f32* feats = (f32*)alloc((size_t)16*5040*4);
  f32* rfeat = (f32*)alloc((size_t)16*512*4);
  f32* ydc   = (f32*)alloc((size_t)2*16*768*4);
  int* meta  = (int*)alloc(128*4);
  u16* wfrag = (u16*)alloc((size_t)4*196608*2);
  f32* xwb   = (f32*)alloc((size_t)2*1024*16*768*4);
  f32* h0    = (f32*)alloc((size_t)16*1024*512*4);
  f32* h1p   = (f32*)alloc((size_t)16*1024*512*4);

  k_meta<<<1,64,0,stream>>>(lengths, meta);
  k_wfrag<<<3072,256,0,stream>>>(g0f_whh, g0b_whh, g1f_whh, g1b_whh, wfrag);
  for (int i=0;i<4;i++){
    int np = Hp[i]*Wpp[i];
    k_conv1<<<dim3((np+255)/256,16),256,0,stream>>>(batch, c1w[i], c1b[i], bn8g,bn8b,bn8m,bn8v,
                                                    r1[i], K1[i], S1[i], Hp[i], Wpp[i]);
  }
  for (int i=0;i<4;i++){
    int np = Ho2[i]*Wo2[i];
    k_conv2<<<dim3((np+255)/256,16),256,0,stream>>>(r1[i], c2w[i], c2b[i], bn3g,bn3b,bn3m,bn3v,
                                                    r2[i], K2[i], S2[i], Hp[i], Wpp[i], Ho2[i], Wo2[i]);
  }
  for (int i=0;i<4;i++){
    int tot = 16*3*Hr[i]*Wr[i];
    k_resize<<<(tot+255)/256,256,0,stream>>>(r2[i], meta, feats, Ho2[i], Wo2[i], Hr[i], Wr[i], Foff[i], i);
  }
  k_fc1<<<dim3(16,8),256,0,stream>>>(feats, fc1w, fc1b, rfeat);
  k_ydc<<<96,256,0,stream>>>(rfeat, g0f_wih, g0b_wih, g0f_bih, g0b_bih, ydc);
  k_xw<0><<<dim3(256,12,2),256,0,stream>>>(batch, g0f_wih, g0b_wih, nullptr, nullptr, ydc, g0f_bhh, g0b_bhh, lengths, xwb);
  k_recur<0><<<dim3(8,2),512,0,stream>>>(xwb, wfrag, g0f_bhh, g0b_bhh, lengths, h0);
  k_xw<1><<<dim3(256,12,2),256,0,stream>>>(h0, g1f_wih, g1b_wih, g1f_bih, g1b_bih, nullptr, g1f_bhh, g1b_bhh, lengths, xwb);
  k_recur<1><<<dim3(8,2),512,0,stream>>>(xwb, wfrag, g1f_bhh, g1b_bhh, lengths, h1p);
  k_final<<<dim3(1024,16),256,0,stream>>>(h1p, fcw, fcb, lengths, meta, out);
}